// Round 4
// baseline (723.644 us; speedup 1.0000x reference)
//
#include <hip/hip_runtime.h>
#include <hip/hip_bf16.h>

// ---------------------------------------------------------------------------
// MLDecoder classification head, MI355X bf16-MFMA implementation.
// B=64, C_IN=2048, H=W=14 (S=196), D=768, FF=2048, G=100, NC=9605, NH=8, HD=96
// ---------------------------------------------------------------------------

#define B_    64
#define CIN_  2048
#define S_    196
#define D_    768
#define FF_   2048
#define G_    100
#define NC_   9605
#define NH_   8
#define HD_   96
#define DF_   97
#define FP_   112          // DF_ padded to 16
#define GP_   112          // G padded to 16
#define SP_   224          // S padded to 32 (7 K-steps) for P / V^T
#define KVW_  1536         // fused K|V row width
#define BS_   (B_ * S_)   // 12544
#define BG_   (B_ * G_)   // 6400

typedef __bf16 bf16x8 __attribute__((ext_vector_type(8)));
typedef float  f32x4  __attribute__((ext_vector_type(4)));

__device__ __forceinline__ float bf2f(ushort u) {
  union { unsigned int i; float f; } v; v.i = ((unsigned int)u) << 16; return v.f;
}
__device__ __forceinline__ ushort f2bf(float f) {
  __hip_bfloat16 h = __float2bfloat16(f);
  return *reinterpret_cast<ushort*>(&h);
}

// async global->LDS, 16 bytes per lane. LDS target must be wave-uniform base
// + lane*16 (our staging layouts satisfy this: lds byte offset == 16*i, i linear in t).
__device__ __forceinline__ void gl2lds16(const ushort* g, ushort* l) {
  __builtin_amdgcn_global_load_lds((const __attribute__((address_space(1))) unsigned int*)g,
                                   (__attribute__((address_space(3))) unsigned int*)l, 16, 0, 0);
}

// ---------------- fp32 -> bf16 bulk convert (n divisible by 4) -------------
__global__ void k_cvt4(const float* __restrict__ in, ushort* __restrict__ out, int n4) {
  int i = blockIdx.x * blockDim.x + threadIdx.x;
  int stride = gridDim.x * blockDim.x;
  for (; i < n4; i += stride) {
    float4 v = ((const float4*)in)[i];
    ushort4 o;
    o.x = f2bf(v.x); o.y = f2bf(v.y); o.z = f2bf(v.z); o.w = f2bf(v.w);
    ((ushort4*)out)[i] = o;
  }
}

// ---------------- pack bk|bv -> bkv [1536] ---------------------------------
__global__ void k_packb(const float* __restrict__ bk, const float* __restrict__ bv,
                        float* __restrict__ bkv) {
  int i = blockIdx.x * 256 + threadIdx.x;
  if (i < D_) bkv[i] = bk[i];
  else if (i < 2 * D_) bkv[i] = bv[i - D_];
}

// ---------------- x [B][C][S] fp32 -> A_emb [B*S][C] bf16 ------------------
// grid (CIN/32, ceil(S/32)=7, B), block 256
__global__ __launch_bounds__(256) void k_xpose(const float* __restrict__ x, ushort* __restrict__ A) {
  __shared__ float tile[32][33];
  const int c0 = blockIdx.x * 32, s0 = blockIdx.y * 32, b = blockIdx.z;
  const int tx = threadIdx.x & 31, ty = threadIdx.x >> 5;   // ty in 0..7
  const float* xb = x + (size_t)b * CIN_ * S_;
  #pragma unroll
  for (int r = 0; r < 32; r += 8) {
    int c = c0 + ty + r, s = s0 + tx;
    tile[ty + r][tx] = (s < S_) ? xb[(size_t)c * S_ + s] : 0.f;
  }
  __syncthreads();
  #pragma unroll
  for (int r = 0; r < 32; r += 8) {
    int s = s0 + ty + r, c = c0 + tx;
    if (s < S_) A[((size_t)(b * S_ + s)) * CIN_ + c] = f2bf(tile[tx][ty + r]);
  }
}

// ------- dup_pool [g][d=768][f=97] fp32 -> dupT [g][f=112][d=768] bf16 -----
__global__ __launch_bounds__(256) void k_dupT(const float* __restrict__ dup, ushort* __restrict__ dupT) {
  __shared__ float tile[32][33];
  const int f0 = blockIdx.x * 32, d0 = blockIdx.y * 32, g = blockIdx.z;
  const int tx = threadIdx.x & 31, ty = threadIdx.x >> 5;
  #pragma unroll
  for (int r = 0; r < 32; r += 8) {
    int d = d0 + ty + r, f = f0 + tx;
    tile[ty + r][tx] = (f < DF_) ? dup[(size_t)g * D_ * DF_ + (size_t)d * DF_ + f] : 0.f;
  }
  __syncthreads();
  #pragma unroll
  for (int r = 0; r < 32; r += 8) {
    int f = f0 + ty + r, d = d0 + tx;
    if (f < FP_) dupT[((size_t)g * FP_ + f) * D_ + d] = f2bf(tile[tx][ty + r]);
  }
}

// ------- KVb [(b,s)][1536] (V at col 768) -> VbT [(b,h)][96][224], s padded -
// grid (7, 3, 512), block 256
__global__ __launch_bounds__(256) void k_vT(const ushort* __restrict__ KVb, ushort* __restrict__ VbT) {
  __shared__ ushort tile[32][33];
  const int s0 = blockIdx.x * 32, d0 = blockIdx.y * 32, bh = blockIdx.z;
  const int b = bh >> 3, h = bh & 7;
  const int tx = threadIdx.x & 31, ty = threadIdx.x >> 5;
  #pragma unroll
  for (int r = 0; r < 32; r += 8) {
    int s = s0 + ty + r, d = d0 + tx;
    tile[ty + r][tx] = (s < S_) ? KVb[((size_t)(b * S_ + s)) * KVW_ + D_ + h * HD_ + d] : (ushort)0;
  }
  __syncthreads();
  #pragma unroll
  for (int r = 0; r < 32; r += 8) {
    int d = d0 + ty + r, s = s0 + tx;
    VbT[((size_t)bh * HD_ + d) * SP_ + s] = tile[tx][ty + r];
  }
}

// ---------------- tgt = LN(2*query_embed)*g1 + be1  [G,768] fp32 -----------
__global__ __launch_bounds__(256) void k_tgt(const float* __restrict__ qe,
    const float* __restrict__ g1, const float* __restrict__ be1, float* __restrict__ tgt) {
  const int g = blockIdx.x, t = threadIdx.x;
  __shared__ float r1[256], r2[256];
  float y[3]; float s = 0.f, sq = 0.f;
  const float* row = qe + (size_t)g * D_;
  #pragma unroll
  for (int i = 0; i < 3; ++i) { float v = 2.f * row[t + i * 256]; y[i] = v; s += v; sq += v * v; }
  r1[t] = s; r2[t] = sq; __syncthreads();
  for (int o = 128; o > 0; o >>= 1) { if (t < o) { r1[t] += r1[t + o]; r2[t] += r2[t + o]; } __syncthreads(); }
  const float mean = r1[0] * (1.f / D_);
  const float var  = r2[0] * (1.f / D_) - mean * mean;
  const float w = rsqrtf(var + 1e-5f);
  #pragma unroll
  for (int i = 0; i < 3; ++i) { int d = t + i * 256; tgt[(size_t)g * D_ + d] = (y[i] - mean) * w * g1[d] + be1[d]; }
}

// ---------------- q = tgt @ wq^T + bq   [112,768] bf16 (rows>=100 zero) ----
__global__ __launch_bounds__(256) void k_qproj(const float* __restrict__ tgt,
    const float* __restrict__ wq, const float* __restrict__ bq, ushort* __restrict__ q) {
  const int g = blockIdx.x, t = threadIdx.x;
  if (g >= G_) {
    for (int e = t; e < D_; e += 256) q[(size_t)g * D_ + e] = 0;
    return;
  }
  __shared__ float ts[D_];
  for (int d = t; d < D_; d += 256) ts[d] = tgt[(size_t)g * D_ + d];
  __syncthreads();
  for (int e = t; e < D_; e += 256) {
    const float* w = wq + (size_t)e * D_;
    float acc = bq[e];
    for (int d = 0; d < D_; d += 4) {
      float4 wv = *(const float4*)&w[d];
      acc += ts[d] * wv.x + ts[d + 1] * wv.y + ts[d + 2] * wv.z + ts[d + 3] * wv.w;
    }
    q[(size_t)g * D_ + e] = f2bf(acc);
  }
}

// ---------------- bf16 MFMA GEMM: C[M,N] = A[M,K] * B[N,K]^T + bias --------
// 128x128 tile, BK=64, 256 threads (4 waves, each 64x64 = 4x4 of 16x16x32)
__global__ __launch_bounds__(256) void k_gemm(const ushort* __restrict__ A, const ushort* __restrict__ B,
    const float* __restrict__ bias, float* __restrict__ Cf, ushort* __restrict__ Cb,
    int M, int N, int K, int relu) {
  __shared__ ushort As[128 * 64];   // 16 KB
  __shared__ ushort Bs[128 * 64];   // 16 KB
  const int t = threadIdx.x;
  const int m0 = blockIdx.y * 128, n0 = blockIdx.x * 128;
  const int lane = t & 63, wave = t >> 6;
  const int quad = lane >> 4, lrow = lane & 15;
  const int wr = (wave >> 1) * 64, wc = (wave & 1) * 64;
  f32x4 acc[4][4] = {};
  for (int k0 = 0; k0 < K; k0 += 64) {
    #pragma unroll
    for (int j = 0; j < 4; ++j) {
      const int i = j * 256 + t;            // chunk id, lds byte off = 16*i
      const int row = i >> 3, col = (i & 7) * 8;
      gl2lds16(A + (size_t)(m0 + row) * K + k0 + col, &As[i * 8]);
      gl2lds16(B + (size_t)(n0 + row) * K + k0 + col, &Bs[i * 8]);
    }
    __syncthreads();
    #pragma unroll
    for (int ks = 0; ks < 2; ++ks) {
      bf16x8 af[4], bfr[4];
      #pragma unroll
      for (int i = 0; i < 4; ++i) af[i] = *(const bf16x8*)&As[(wr + i * 16 + lrow) * 64 + ks * 32 + quad * 8];
      #pragma unroll
      for (int j = 0; j < 4; ++j) bfr[j] = *(const bf16x8*)&Bs[(wc + j * 16 + lrow) * 64 + ks * 32 + quad * 8];
      #pragma unroll
      for (int i = 0; i < 4; ++i)
        #pragma unroll
        for (int j = 0; j < 4; ++j)
          acc[i][j] = __builtin_amdgcn_mfma_f32_16x16x32_bf16(af[i], bfr[j], acc[i][j], 0, 0, 0);
    }
    __syncthreads();
  }
  #pragma unroll
  for (int i = 0; i < 4; ++i) {
    #pragma unroll
    for (int j = 0; j < 4; ++j) {
      const int gcol = n0 + wc + j * 16 + lrow;
      const float bv = bias ? bias[gcol] : 0.f;
      #pragma unroll
      for (int r = 0; r < 4; ++r) {
        const int grow = m0 + wr + i * 16 + quad * 4 + r;
        float v = acc[i][j][r] + bv;
        if (relu) v = fmaxf(v, 0.f);
        if (Cf) Cf[(size_t)grow * N + gcol] = v;
        else    Cb[(size_t)grow * N + gcol] = f2bf(v);
      }
    }
  }
}

// ---------------- scores + in-register softmax -> P bf16 [bh][112][224] ----
// grid (NH, B), block 256. MFMA QK^T, K staged via global_load_lds (stride KVW_).
__global__ __launch_bounds__(256) void k_scores(const ushort* __restrict__ qB,
    const ushort* __restrict__ KVb, ushort* __restrict__ attnP) {
  __shared__ ushort Ks[208 * HD_];   // 39936 B
  const int h = blockIdx.x, b = blockIdx.y, t = threadIdx.x;
  const int bh = b * NH_ + h;
  const int lane = t & 63, wave = t >> 6;
  const int quad = lane >> 4, c = lane & 15;
  // stage K rows 0..207 (rows >=196 read in-bounds-of-ws garbage, masked below)
  for (int i = t; i < 208 * 12; i += 256) {
    int r = i / 12, col = (i % 12) * 8;
    gl2lds16(KVb + ((size_t)(b * S_ + r)) * KVW_ + h * HD_ + col, &Ks[i * 8]);
  }
  __syncthreads();
  const float scale = 0.1020620726f;  // 1/sqrt(96)
  for (int ii = wave; ii < 7; ii += 4) {
    f32x4 acc[13] = {};
    bf16x8 af[3];
    #pragma unroll
    for (int ks = 0; ks < 3; ++ks)
      af[ks] = *(const bf16x8*)(qB + ((size_t)(ii * 16 + c)) * D_ + h * HD_ + ks * 32 + quad * 8);
    #pragma unroll
    for (int j = 0; j < 13; ++j) {
      #pragma unroll
      for (int ks = 0; ks < 3; ++ks) {
        bf16x8 bf = *(const bf16x8*)&Ks[(j * 16 + c) * HD_ + ks * 32 + quad * 8];
        acc[j] = __builtin_amdgcn_mfma_f32_16x16x32_bf16(af[ks], bf, acc[j], 0, 0, 0);
      }
    }
    // softmax: row g = ii*16 + quad*4 + r lives in the 16-lane cluster (c = s-offset)
    float m[4] = {-1e30f, -1e30f, -1e30f, -1e30f};
    #pragma unroll
    for (int j = 0; j < 13; ++j)
      #pragma unroll
      for (int r = 0; r < 4; ++r) {
        float v = acc[j][r] * scale;
        if (j == 12 && c >= 4) v = -1e30f;   // mask padded s in 196..207
        acc[j][r] = v;
        m[r] = fmaxf(m[r], v);
      }
    #pragma unroll
    for (int r = 0; r < 4; ++r) {
      m[r] = fmaxf(m[r], __shfl_xor(m[r], 1));
      m[r] = fmaxf(m[r], __shfl_xor(m[r], 2));
      m[r] = fmaxf(m[r], __shfl_xor(m[r], 4));
      m[r] = fmaxf(m[r], __shfl_xor(m[r], 8));
    }
    float l[4] = {0.f, 0.f, 0.f, 0.f};
    #pragma unroll
    for (int j = 0; j < 13; ++j)
      #pragma unroll
      for (int r = 0; r < 4; ++r) {
        float e = __expf(acc[j][r] - m[r]);
        acc[j][r] = e; l[r] += e;
      }
    #pragma unroll
    for (int r = 0; r < 4; ++r) {
      l[r] += __shfl_xor(l[r], 1);
      l[r] += __shfl_xor(l[r], 2);
      l[r] += __shfl_xor(l[r], 4);
      l[r] += __shfl_xor(l[r], 8);
      l[r] = 1.f / l[r];
    }
    #pragma unroll
    for (int j = 0; j < 13; ++j)
      #pragma unroll
      for (int r = 0; r < 4; ++r) {
        const int g = ii * 16 + quad * 4 + r;
        attnP[((size_t)bh * GP_ + g) * SP_ + j * 16 + c] = f2bf(acc[j][r] * l[r]);
      }
  }
}

// ---------------- ctx = P @ V via MFMA, V^T staged in LDS ------------------
// grid (NH, B), block 256. P A-frags direct from global.
__global__ __launch_bounds__(256) void k_pv(const ushort* __restrict__ attnP,
    const ushort* __restrict__ VbT, ushort* __restrict__ ctx) {
  __shared__ ushort Vs[HD_ * SP_];   // 43008 B
  const int h = blockIdx.x, b = blockIdx.y, t = threadIdx.x;
  const int bh = b * NH_ + h;
  const int lane = t & 63, wave = t >> 6;
  const int quad = lane >> 4, c = lane & 15;
  const ushort* vsrc = VbT + (size_t)bh * HD_ * SP_;
  for (int i = t; i < HD_ * SP_ / 8; i += 256)   // 2688 chunks
    gl2lds16(vsrc + (size_t)i * 8, &Vs[i * 8]);
  __syncthreads();
  for (int ii = wave; ii < 7; ii += 4) {
    bf16x8 af[7];
    #pragma unroll
    for (int k = 0; k < 7; ++k)
      af[k] = *(const bf16x8*)(attnP + ((size_t)bh * GP_ + ii * 16 + c) * SP_ + k * 32 + quad * 8);
    #pragma unroll
    for (int j = 0; j < 6; ++j) {
      f32x4 acc = {};
      #pragma unroll
      for (int k = 0; k < 7; ++k) {
        bf16x8 bf = *(const bf16x8*)&Vs[(j * 16 + c) * SP_ + k * 32 + quad * 8];
        acc = __builtin_amdgcn_mfma_f32_16x16x32_bf16(af[k], bf, acc, 0, 0, 0);
      }
      #pragma unroll
      for (int r = 0; r < 4; ++r) {
        const int g = ii * 16 + quad * 4 + r;
        if (g < G_)
          ctx[((size_t)(b * G_ + g)) * D_ + h * HD_ + j * 16 + c] = f2bf(acc[r]);
      }
    }
  }
}

// ---------------- residual + LayerNorm -------------------------------------
__global__ __launch_bounds__(256) void k_lnres(const float* __restrict__ resid, int resid_mod,
    const float* __restrict__ add, const float* __restrict__ gamma, const float* __restrict__ beta,
    float* __restrict__ outf, ushort* __restrict__ outb) {
  const int row = blockIdx.x, t = threadIdx.x;
  __shared__ float r1[256], r2[256];
  const float* rrow = resid + (size_t)(resid_mod ? (row % G_) : row) * D_;
  const float* arow = add + (size_t)row * D_;
  float y[3]; float s = 0.f, sq = 0.f;
  #pragma unroll
  for (int i = 0; i < 3; ++i) {
    int d = t + i * 256;
    float v = rrow[d] + arow[d];
    y[i] = v; s += v; sq += v * v;
  }
  r1[t] = s; r2[t] = sq; __syncthreads();
  for (int o = 128; o > 0; o >>= 1) { if (t < o) { r1[t] += r1[t + o]; r2[t] += r2[t + o]; } __syncthreads(); }
  const float mean = r1[0] * (1.f / D_);
  const float var  = r2[0] * (1.f / D_) - mean * mean;
  const float w = rsqrtf(var + 1e-5f);
  #pragma unroll
  for (int i = 0; i < 3; ++i) {
    int d = t + i * 256;
    float v = (y[i] - mean) * w * gamma[d] + beta[d];
    if (outf) outf[(size_t)row * D_ + d] = v;
    if (outb) outb[(size_t)row * D_ + d] = f2bf(v);
  }
}

// ---------------- grouped head via MFMA, LDS-free --------------------------
// grid (G, 7), block 256. Each block: one 16-col f-tile of one group.
// A (h) and B (dupT) frags read straight from global (k-contiguous), no barriers.
__global__ __launch_bounds__(256) void k_head3(const ushort* __restrict__ h,
    const ushort* __restrict__ dupT, const float* __restrict__ dup_bias, float* __restrict__ out) {
  const int g = blockIdx.x, j = blockIdx.y, t = threadIdx.x;
  const int lane = t & 63, wave = t >> 6;
  const int quad = lane >> 4, c = lane & 15;
  const ushort* ap = h + ((size_t)(wave * 16 + c) * G_ + g) * D_;
  const ushort* bp = dupT + ((size_t)g * FP_ + j * 16 + c) * D_;
  f32x4 acc = {};
  #pragma unroll 8
  for (int k0 = 0; k0 < D_; k0 += 32) {
    bf16x8 af = *(const bf16x8*)(ap + k0 + quad * 8);
    bf16x8 bf = *(const bf16x8*)(bp + k0 + quad * 8);
    acc = __builtin_amdgcn_mfma_f32_16x16x32_bf16(af, bf, acc, 0, 0, 0);
  }
  const int f = j * 16 + c;
  if (f >= DF_) return;
  const int n = g * DF_ + f;
  if (n >= NC_) return;
  const float bv = dup_bias[n];
  #pragma unroll
  for (int r = 0; r < 4; ++r) {
    const int b = wave * 16 + quad * 4 + r;
    out[(size_t)b * NC_ + n] = acc[r] + bv;
  }
}

// ---------------------------------------------------------------------------
// workspace layout (bytes)
// region 0 (0..51.4 MB): aemb (embed A), then attnP+VbT (attention), then ffB/ffoF (FFN)
// ---------------------------------------------------------------------------
static constexpr size_t OFF_AEMB  = 0;          // bf16 [12544,2048] = 51,380,224
static constexpr size_t OFF_ATTNP = 0;          // bf16 [512,112,224] = 25,690,112
static constexpr size_t OFF_VBT   = 25690112;   // bf16 [512,96,224]  = 22,020,096 (end 47,710,208)
static constexpr size_t OFF_FF    = 0;          // bf16 [6400,2048] = 26,214,400
static constexpr size_t OFF_FFO   = 26214400;   // f32  [6400,768]  = 19,660,800 (end 45,875,200)
static constexpr size_t OFF_WEMB  = 51380224;   // bf16 3,145,728
static constexpr size_t OFF_MEM   = 54525952;   // bf16 [12544,768] = 19,267,584
static constexpr size_t OFF_WK    = 73793536;   // 1,179,648   (wk|wv contiguous = fused 1536x768)
static constexpr size_t OFF_WV    = 74973184;   // 1,179,648
static constexpr size_t OFF_WO    = 76152832;   // 1,179,648
static constexpr size_t OFF_W1    = 77332480;   // 3,145,728
static constexpr size_t OFF_W2    = 80478208;   // 3,145,728
static constexpr size_t OFF_DUP   = 83623936;   // bf16 [100,112,768] = 17,203,200
static constexpr size_t OFF_KV    = 100827136;  // bf16 [12544,1536] = 38,535,168 (end 139,362,304)
static constexpr size_t OFF_TGT   = 139362304;  // 307,200
static constexpr size_t OFF_Q     = 139669504;  // bf16 [112,768] = 172,032
static constexpr size_t OFF_BKV   = 139841536;  // f32 [1536] = 6,144
static constexpr size_t OFF_CTX   = 139976704;  // 9,830,400
static constexpr size_t OFF_CTXO  = 149807104;  // 19,660,800
static constexpr size_t OFF_TGT2F = 169467904;  // 19,660,800
static constexpr size_t OFF_TGT2B = 189128704;  // 9,830,400
static constexpr size_t OFF_HB    = 198959104;  // 9,830,400  (end 208,789,504)

extern "C" void kernel_launch(void* const* d_in, const int* in_sizes, int n_in,
                              void* d_out, int out_size, void* d_ws, size_t ws_size,
                              hipStream_t stream) {
  const float* x           = (const float*)d_in[0];
  const float* w_embed     = (const float*)d_in[1];
  const float* b_embed     = (const float*)d_in[2];
  const float* query_embed = (const float*)d_in[3];
  const float* wq          = (const float*)d_in[4];
  const float* bq          = (const float*)d_in[5];
  const float* wk          = (const float*)d_in[6];
  const float* bk          = (const float*)d_in[7];
  const float* wv          = (const float*)d_in[8];
  const float* bv          = (const float*)d_in[9];
  const float* wo          = (const float*)d_in[10];
  const float* bo          = (const float*)d_in[11];
  const float* g1          = (const float*)d_in[12];
  const float* be1         = (const float*)d_in[13];
  const float* g2          = (const float*)d_in[14];
  const float* be2         = (const float*)d_in[15];
  const float* g3          = (const float*)d_in[16];
  const float* be3         = (const float*)d_in[17];
  const float* w1          = (const float*)d_in[18];
  const float* bl1         = (const float*)d_in[19];
  const float* w2          = (const float*)d_in[20];
  const float* bl2         = (const float*)d_in[21];
  const float* dup_pool    = (const float*)d_in[22];
  const float* dup_bias    = (const float*)d_in[23];
  float* out = (float*)d_out;
  char* ws = (char*)d_ws;

  ushort* aemb  = (ushort*)(ws + OFF_AEMB);
  ushort* wembB = (ushort*)(ws + OFF_WEMB);
  ushort* memB  = (ushort*)(ws + OFF_MEM);
  ushort* wkvB  = (ushort*)(ws + OFF_WK);    // fused [1536][768]
  ushort* wkB   = (ushort*)(ws + OFF_WK);
  ushort* wvB   = (ushort*)(ws + OFF_WV);
  ushort* woB   = (ushort*)(ws + OFF_WO);
  ushort* w1B   = (ushort*)(ws + OFF_W1);
  ushort* w2B   = (ushort*)(ws + OFF_W2);
  ushort* dupT  = (ushort*)(ws + OFF_DUP);
  ushort* KVb   = (ushort*)(ws + OFF_KV);
  float*  tgtF  = (float*)(ws + OFF_TGT);
  ushort* qB    = (ushort*)(ws + OFF_Q);
  float*  bkvF  = (float*)(ws + OFF_BKV);
  ushort* attnP = (ushort*)(ws + OFF_ATTNP);
  ushort* VbT   = (ushort*)(ws + OFF_VBT);
  ushort* ctxB  = (ushort*)(ws + OFF_CTX);
  float*  ctxoF = (float*)(ws + OFF_CTXO);
  float*  tgt2F = (float*)(ws + OFF_TGT2F);
  ushort* tgt2B = (ushort*)(ws + OFF_TGT2B);
  ushort* ffB   = (ushort*)(ws + OFF_FF);
  float*  ffoF  = (float*)(ws + OFF_FFO);
  ushort* hB    = (ushort*)(ws + OFF_HB);

  // 1. weight conversions to bf16 (+ dup transpose, bias pack)
  k_cvt4<<<1024, 256, 0, stream>>>(w_embed,  wembB, D_ * CIN_ / 4);
  k_cvt4<<<1024, 256, 0, stream>>>(wk,       wkB,   D_ * D_ / 4);
  k_cvt4<<<1024, 256, 0, stream>>>(wv,       wvB,   D_ * D_ / 4);
  k_cvt4<<<1024, 256, 0, stream>>>(wo,       woB,   D_ * D_ / 4);
  k_cvt4<<<1024, 256, 0, stream>>>(w1,       w1B,   FF_ * D_ / 4);
  k_cvt4<<<1024, 256, 0, stream>>>(w2,       w2B,   D_ * FF_ / 4);
  k_packb<<<6, 256, 0, stream>>>(bk, bv, bkvF);
  k_dupT<<<dim3(4, 24, G_), 256, 0, stream>>>(dup_pool, dupT);

  // 2. x transpose+convert -> A_emb [B*S, C]
  k_xpose<<<dim3(CIN_ / 32, 7, B_), 256, 0, stream>>>(x, aemb);

  // 3-4. tgt = LN(2*query_embed), qB = bf16(tgt@wq^T + bq) (batch-independent)
  k_tgt<<<G_, 256, 0, stream>>>(query_embed, g1, be1, tgtF);
  k_qproj<<<GP_, 256, 0, stream>>>(tgtF, wq, bq, qB);

  // 5. embed GEMM + relu -> mem bf16 [12544, 768]
  k_gemm<<<dim3(D_ / 128, BS_ / 128), 256, 0, stream>>>(aemb, wembB, b_embed, nullptr, memB,
                                                        BS_, D_, CIN_, 1);
  // 6. fused K|V projection -> bf16 [12544, 1536]
  k_gemm<<<dim3(KVW_ / 128, BS_ / 128), 256, 0, stream>>>(memB, wkvB, bkvF, nullptr, KVb,
                                                          BS_, KVW_, D_, 0);

  // 7. V transpose for PV B-operand
  k_vT<<<dim3(7, 3, B_ * NH_), 256, 0, stream>>>(KVb, VbT);

  // 8-9. MFMA attention
  k_scores<<<dim3(NH_, B_), 256, 0, stream>>>(qB, KVb, attnP);
  k_pv<<<dim3(NH_, B_), 256, 0, stream>>>(attnP, VbT, ctxB);

  // 10. ctx @ wo^T + bo -> fp32 [6400, 768]
  k_gemm<<<dim3(D_ / 128, BG_ / 128), 256, 0, stream>>>(ctxB, woB, bo, ctxoF, nullptr, BG_, D_, D_, 0);

  // 11. tgt2 = LN(tgt + ctxo)
  k_lnres<<<BG_, 256, 0, stream>>>(tgtF, 1, ctxoF, g2, be2, tgt2F, tgt2B);

  // 12-13. FFN
  k_gemm<<<dim3(FF_ / 128, BG_ / 128), 256, 0, stream>>>(tgt2B, w1B, bl1, nullptr, ffB, BG_, FF_, D_, 1);
  k_gemm<<<dim3(D_ / 128, BG_ / 128), 256, 0, stream>>>(ffB, w2B, bl2, ffoF, nullptr, BG_, D_, FF_, 0);

  // 14. h = LN(tgt2 + ffo) -> bf16
  k_lnres<<<BG_, 256, 0, stream>>>(tgt2F, 0, ffoF, g3, be3, nullptr, hB);

  // 15. grouped head -> logits fp32 [64, 9605] via MFMA (LDS-free)
  k_head3<<<dim3(G_, 7), 256, 0, stream>>>(hB, dupT, dup_bias, out);
}

// Round 5
// 683.669 us; speedup vs baseline: 1.0585x; 1.0585x over previous
//
#include <hip/hip_runtime.h>
#include <hip/hip_bf16.h>

// ---------------------------------------------------------------------------
// MLDecoder classification head, MI355X bf16-MFMA implementation.
// B=64, C_IN=2048, H=W=14 (S=196), D=768, FF=2048, G=100, NC=9605, NH=8, HD=96
// ---------------------------------------------------------------------------

#define B_    64
#define CIN_  2048
#define S_    196
#define D_    768
#define FF_   2048
#define G_    100
#define NC_   9605
#define NH_   8
#define HD_   96
#define DF_   97
#define FP_   112          // DF_ padded to 16
#define GP_   112          // G padded to 16
#define SP_   224          // S padded to 32 (7 K-steps) for P / V^T
#define KVW_  1536         // fused K|V row width
#define BS_   (B_ * S_)   // 12544
#define BG_   (B_ * G_)   // 6400

typedef __bf16 bf16x8 __attribute__((ext_vector_type(8)));
typedef float  f32x4  __attribute__((ext_vector_type(4)));

__device__ __forceinline__ float bf2f(ushort u) {
  union { unsigned int i; float f; } v; v.i = ((unsigned int)u) << 16; return v.f;
}
__device__ __forceinline__ ushort f2bf(float f) {
  __hip_bfloat16 h = __float2bfloat16(f);
  return *reinterpret_cast<ushort*>(&h);
}

// async global->LDS, 16 bytes per lane. LDS target must be wave-uniform base
// + lane*16 (our staging layouts satisfy this: lds byte offset == 16*i, i linear in t).
__device__ __forceinline__ void gl2lds16(const ushort* g, ushort* l) {
  __builtin_amdgcn_global_load_lds((const __attribute__((address_space(1))) unsigned int*)g,
                                   (__attribute__((address_space(3))) unsigned int*)l, 16, 0, 0);
}

// ---------------- all weight fp32 -> bf16 converts in ONE kernel -----------
struct CvtArgs {
  const float* src[6];
  ushort*      dst[6];
  int          n4[6];    // float4 chunks per segment
  int          total;    // sum n4
};
__global__ void k_cvtall(CvtArgs a) {
  int i = blockIdx.x * blockDim.x + threadIdx.x;
  const int stride = gridDim.x * blockDim.x;
  for (; i < a.total; i += stride) {
    int seg = 0, off = i;
    while (off >= a.n4[seg]) { off -= a.n4[seg]; ++seg; }
    float4 v = ((const float4*)a.src[seg])[off];
    ushort4 o;
    o.x = f2bf(v.x); o.y = f2bf(v.y); o.z = f2bf(v.z); o.w = f2bf(v.w);
    ((ushort4*)a.dst[seg])[off] = o;
  }
}

// ---------------- pack bk|bv -> bkv [1536] ---------------------------------
__global__ void k_packb(const float* __restrict__ bk, const float* __restrict__ bv,
                        float* __restrict__ bkv) {
  int i = blockIdx.x * 256 + threadIdx.x;
  if (i < D_) bkv[i] = bk[i];
  else if (i < 2 * D_) bkv[i] = bv[i - D_];
}

// ---------------- x [B][C][S] fp32 -> A_emb [B*S][C] bf16 ------------------
// grid (CIN/32, ceil(S/32)=7, B), block 256
__global__ __launch_bounds__(256) void k_xpose(const float* __restrict__ x, ushort* __restrict__ A) {
  __shared__ float tile[32][33];
  const int c0 = blockIdx.x * 32, s0 = blockIdx.y * 32, b = blockIdx.z;
  const int tx = threadIdx.x & 31, ty = threadIdx.x >> 5;   // ty in 0..7
  const float* xb = x + (size_t)b * CIN_ * S_;
  #pragma unroll
  for (int r = 0; r < 32; r += 8) {
    int c = c0 + ty + r, s = s0 + tx;
    tile[ty + r][tx] = (s < S_) ? xb[(size_t)c * S_ + s] : 0.f;
  }
  __syncthreads();
  #pragma unroll
  for (int r = 0; r < 32; r += 8) {
    int s = s0 + ty + r, c = c0 + tx;
    if (s < S_) A[((size_t)(b * S_ + s)) * CIN_ + c] = f2bf(tile[tx][ty + r]);
  }
}

// ------- dup_pool [g][d=768][f=97] fp32 -> dupT [g][f=112][d=768] bf16 -----
__global__ __launch_bounds__(256) void k_dupT(const float* __restrict__ dup, ushort* __restrict__ dupT) {
  __shared__ float tile[32][33];
  const int f0 = blockIdx.x * 32, d0 = blockIdx.y * 32, g = blockIdx.z;
  const int tx = threadIdx.x & 31, ty = threadIdx.x >> 5;
  #pragma unroll
  for (int r = 0; r < 32; r += 8) {
    int d = d0 + ty + r, f = f0 + tx;
    tile[ty + r][tx] = (f < DF_) ? dup[(size_t)g * D_ * DF_ + (size_t)d * DF_ + f] : 0.f;
  }
  __syncthreads();
  #pragma unroll
  for (int r = 0; r < 32; r += 8) {
    int f = f0 + ty + r, d = d0 + tx;
    if (f < FP_) dupT[((size_t)g * FP_ + f) * D_ + d] = f2bf(tile[tx][ty + r]);
  }
}

// ------- KVb [(b,s)][1536] (V at col 768) -> VbT [(b,h)][96][224], s padded -
// grid (7, 3, 512), block 256
__global__ __launch_bounds__(256) void k_vT(const ushort* __restrict__ KVb, ushort* __restrict__ VbT) {
  __shared__ ushort tile[32][33];
  const int s0 = blockIdx.x * 32, d0 = blockIdx.y * 32, bh = blockIdx.z;
  const int b = bh >> 3, h = bh & 7;
  const int tx = threadIdx.x & 31, ty = threadIdx.x >> 5;
  #pragma unroll
  for (int r = 0; r < 32; r += 8) {
    int s = s0 + ty + r, d = d0 + tx;
    tile[ty + r][tx] = (s < S_) ? KVb[((size_t)(b * S_ + s)) * KVW_ + D_ + h * HD_ + d] : (ushort)0;
  }
  __syncthreads();
  #pragma unroll
  for (int r = 0; r < 32; r += 8) {
    int d = d0 + ty + r, s = s0 + tx;
    VbT[((size_t)bh * HD_ + d) * SP_ + s] = tile[tx][ty + r];
  }
}

// ---------------- tgt = LN(2*query_embed)*g1 + be1  [G,768] fp32 -----------
__global__ __launch_bounds__(256) void k_tgt(const float* __restrict__ qe,
    const float* __restrict__ g1, const float* __restrict__ be1, float* __restrict__ tgt) {
  const int g = blockIdx.x, t = threadIdx.x;
  __shared__ float r1[256], r2[256];
  float y[3]; float s = 0.f, sq = 0.f;
  const float* row = qe + (size_t)g * D_;
  #pragma unroll
  for (int i = 0; i < 3; ++i) { float v = 2.f * row[t + i * 256]; y[i] = v; s += v; sq += v * v; }
  r1[t] = s; r2[t] = sq; __syncthreads();
  for (int o = 128; o > 0; o >>= 1) { if (t < o) { r1[t] += r1[t + o]; r2[t] += r2[t + o]; } __syncthreads(); }
  const float mean = r1[0] * (1.f / D_);
  const float var  = r2[0] * (1.f / D_) - mean * mean;
  const float w = rsqrtf(var + 1e-5f);
  #pragma unroll
  for (int i = 0; i < 3; ++i) { int d = t + i * 256; tgt[(size_t)g * D_ + d] = (y[i] - mean) * w * g1[d] + be1[d]; }
}

// ---------------- q = tgt @ wq^T + bq   [112,768] bf16 (rows>=100 zero) ----
__global__ __launch_bounds__(256) void k_qproj(const float* __restrict__ tgt,
    const float* __restrict__ wq, const float* __restrict__ bq, ushort* __restrict__ q) {
  const int g = blockIdx.x, t = threadIdx.x;
  if (g >= G_) {
    for (int e = t; e < D_; e += 256) q[(size_t)g * D_ + e] = 0;
    return;
  }
  __shared__ float ts[D_];
  for (int d = t; d < D_; d += 256) ts[d] = tgt[(size_t)g * D_ + d];
  __syncthreads();
  for (int e = t; e < D_; e += 256) {
    const float* w = wq + (size_t)e * D_;
    float acc = bq[e];
    for (int d = 0; d < D_; d += 4) {
      float4 wv = *(const float4*)&w[d];
      acc += ts[d] * wv.x + ts[d + 1] * wv.y + ts[d + 2] * wv.z + ts[d + 3] * wv.w;
    }
    q[(size_t)g * D_ + e] = f2bf(acc);
  }
}

// ---------------- bf16 MFMA GEMM: C[M,N] = A[M,K] * B[N,K]^T + bias --------
// 128x128 tile, BK=32 (row stride 64 B = 16 banks -> free 2-way aliasing only;
// BK=64 = 32 banks put every row at bank 0 and tripled conflicts: R4 regression)
__global__ __launch_bounds__(256) void k_gemm(const ushort* __restrict__ A, const ushort* __restrict__ B,
    const float* __restrict__ bias, float* __restrict__ Cf, ushort* __restrict__ Cb,
    int M, int N, int K, int relu) {
  __shared__ ushort As[128 * 32];
  __shared__ ushort Bs[128 * 32];
  const int t = threadIdx.x;
  const int m0 = blockIdx.y * 128, n0 = blockIdx.x * 128;
  const int lane = t & 63, wave = t >> 6;
  const int quad = lane >> 4, lrow = lane & 15;
  const int wr = (wave >> 1) * 64, wc = (wave & 1) * 64;
  const int srow = t >> 2, scol = (t & 3) * 8;
  f32x4 acc[4][4] = {};
  for (int k0 = 0; k0 < K; k0 += 32) {
    const ushort* ag = A + (size_t)(m0 + srow) * K + k0 + scol;
    const ushort* bg = B + (size_t)(n0 + srow) * K + k0 + scol;
    gl2lds16(ag,                    &As[srow * 32 + scol]);
    gl2lds16(ag + (size_t)64 * K,   &As[(srow + 64) * 32 + scol]);
    gl2lds16(bg,                    &Bs[srow * 32 + scol]);
    gl2lds16(bg + (size_t)64 * K,   &Bs[(srow + 64) * 32 + scol]);
    __syncthreads();
    bf16x8 af[4], bfr[4];
    #pragma unroll
    for (int i = 0; i < 4; ++i) af[i] = *(const bf16x8*)&As[(wr + i * 16 + lrow) * 32 + quad * 8];
    #pragma unroll
    for (int j = 0; j < 4; ++j) bfr[j] = *(const bf16x8*)&Bs[(wc + j * 16 + lrow) * 32 + quad * 8];
    #pragma unroll
    for (int i = 0; i < 4; ++i)
      #pragma unroll
      for (int j = 0; j < 4; ++j)
        acc[i][j] = __builtin_amdgcn_mfma_f32_16x16x32_bf16(af[i], bfr[j], acc[i][j], 0, 0, 0);
    __syncthreads();
  }
  #pragma unroll
  for (int i = 0; i < 4; ++i) {
    #pragma unroll
    for (int j = 0; j < 4; ++j) {
      const int gcol = n0 + wc + j * 16 + lrow;
      const float bv = bias ? bias[gcol] : 0.f;
      #pragma unroll
      for (int r = 0; r < 4; ++r) {
        const int grow = m0 + wr + i * 16 + quad * 4 + r;
        float v = acc[i][j][r] + bv;
        if (relu) v = fmaxf(v, 0.f);
        if (Cf) Cf[(size_t)grow * N + gcol] = v;
        else    Cb[(size_t)grow * N + gcol] = f2bf(v);
      }
    }
  }
}

// ---------------- scores + in-register softmax -> P bf16 [bh][112][224] ----
// grid (NH, B), block 256. MFMA QK^T, K staged via global_load_lds (stride KVW_).
__global__ __launch_bounds__(256) void k_scores(const ushort* __restrict__ qB,
    const ushort* __restrict__ KVb, ushort* __restrict__ attnP) {
  __shared__ ushort Ks[208 * HD_];   // 39936 B
  const int h = blockIdx.x, b = blockIdx.y, t = threadIdx.x;
  const int bh = b * NH_ + h;
  const int lane = t & 63, wave = t >> 6;
  const int quad = lane >> 4, c = lane & 15;
  // stage K rows 0..207 (rows >=196 read in-bounds-of-ws garbage, masked below)
  for (int i = t; i < 208 * 12; i += 256) {
    int r = i / 12, col = (i % 12) * 8;
    gl2lds16(KVb + ((size_t)(b * S_ + r)) * KVW_ + h * HD_ + col, &Ks[i * 8]);
  }
  __syncthreads();
  const float scale = 0.1020620726f;  // 1/sqrt(96)
  for (int ii = wave; ii < 7; ii += 4) {
    f32x4 acc[13] = {};
    bf16x8 af[3];
    #pragma unroll
    for (int ks = 0; ks < 3; ++ks)
      af[ks] = *(const bf16x8*)(qB + ((size_t)(ii * 16 + c)) * D_ + h * HD_ + ks * 32 + quad * 8);
    #pragma unroll
    for (int j = 0; j < 13; ++j) {
      #pragma unroll
      for (int ks = 0; ks < 3; ++ks) {
        bf16x8 bf = *(const bf16x8*)&Ks[(j * 16 + c) * HD_ + ks * 32 + quad * 8];
        acc[j] = __builtin_amdgcn_mfma_f32_16x16x32_bf16(af[ks], bf, acc[j], 0, 0, 0);
      }
    }
    // softmax: row g = ii*16 + quad*4 + r lives in the 16-lane cluster (c = s-offset)
    float m[4] = {-1e30f, -1e30f, -1e30f, -1e30f};
    #pragma unroll
    for (int j = 0; j < 13; ++j)
      #pragma unroll
      for (int r = 0; r < 4; ++r) {
        float v = acc[j][r] * scale;
        if (j == 12 && c >= 4) v = -1e30f;   // mask padded s in 196..207
        acc[j][r] = v;
        m[r] = fmaxf(m[r], v);
      }
    #pragma unroll
    for (int r = 0; r < 4; ++r) {
      m[r] = fmaxf(m[r], __shfl_xor(m[r], 1));
      m[r] = fmaxf(m[r], __shfl_xor(m[r], 2));
      m[r] = fmaxf(m[r], __shfl_xor(m[r], 4));
      m[r] = fmaxf(m[r], __shfl_xor(m[r], 8));
    }
    float l[4] = {0.f, 0.f, 0.f, 0.f};
    #pragma unroll
    for (int j = 0; j < 13; ++j)
      #pragma unroll
      for (int r = 0; r < 4; ++r) {
        float e = __expf(acc[j][r] - m[r]);
        acc[j][r] = e; l[r] += e;
      }
    #pragma unroll
    for (int r = 0; r < 4; ++r) {
      l[r] += __shfl_xor(l[r], 1);
      l[r] += __shfl_xor(l[r], 2);
      l[r] += __shfl_xor(l[r], 4);
      l[r] += __shfl_xor(l[r], 8);
      l[r] = 1.f / l[r];
    }
    #pragma unroll
    for (int j = 0; j < 13; ++j)
      #pragma unroll
      for (int r = 0; r < 4; ++r) {
        const int g = ii * 16 + quad * 4 + r;
        attnP[((size_t)bh * GP_ + g) * SP_ + j * 16 + c] = f2bf(acc[j][r] * l[r]);
      }
  }
}

// ---------------- ctx = P @ V via MFMA, V^T staged in LDS ------------------
// grid (NH, B), block 256. P A-frags direct from global.
__global__ __launch_bounds__(256) void k_pv(const ushort* __restrict__ attnP,
    const ushort* __restrict__ VbT, ushort* __restrict__ ctx) {
  __shared__ ushort Vs[HD_ * SP_];   // 43008 B
  const int h = blockIdx.x, b = blockIdx.y, t = threadIdx.x;
  const int bh = b * NH_ + h;
  const int lane = t & 63, wave = t >> 6;
  const int quad = lane >> 4, c = lane & 15;
  const ushort* vsrc = VbT + (size_t)bh * HD_ * SP_;
  for (int i = t; i < HD_ * SP_ / 8; i += 256)   // 2688 chunks
    gl2lds16(vsrc + (size_t)i * 8, &Vs[i * 8]);
  __syncthreads();
  for (int ii = wave; ii < 7; ii += 4) {
    bf16x8 af[7];
    #pragma unroll
    for (int k = 0; k < 7; ++k)
      af[k] = *(const bf16x8*)(attnP + ((size_t)bh * GP_ + ii * 16 + c) * SP_ + k * 32 + quad * 8);
    #pragma unroll
    for (int j = 0; j < 6; ++j) {
      f32x4 acc = {};
      #pragma unroll
      for (int k = 0; k < 7; ++k) {
        bf16x8 bf = *(const bf16x8*)&Vs[(j * 16 + c) * SP_ + k * 32 + quad * 8];
        acc = __builtin_amdgcn_mfma_f32_16x16x32_bf16(af[k], bf, acc, 0, 0, 0);
      }
      #pragma unroll
      for (int r = 0; r < 4; ++r) {
        const int g = ii * 16 + quad * 4 + r;
        if (g < G_)
          ctx[((size_t)(b * G_ + g)) * D_ + h * HD_ + j * 16 + c] = f2bf(acc[r]);
      }
    }
  }
}

// ---------------- residual + LayerNorm -------------------------------------
__global__ __launch_bounds__(256) void k_lnres(const float* __restrict__ resid, int resid_mod,
    const float* __restrict__ add, const float* __restrict__ gamma, const float* __restrict__ beta,
    float* __restrict__ outf, ushort* __restrict__ outb) {
  const int row = blockIdx.x, t = threadIdx.x;
  __shared__ float r1[256], r2[256];
  const float* rrow = resid + (size_t)(resid_mod ? (row % G_) : row) * D_;
  const float* arow = add + (size_t)row * D_;
  float y[3]; float s = 0.f, sq = 0.f;
  #pragma unroll
  for (int i = 0; i < 3; ++i) {
    int d = t + i * 256;
    float v = rrow[d] + arow[d];
    y[i] = v; s += v; sq += v * v;
  }
  r1[t] = s; r2[t] = sq; __syncthreads();
  for (int o = 128; o > 0; o >>= 1) { if (t < o) { r1[t] += r1[t + o]; r2[t] += r2[t + o]; } __syncthreads(); }
  const float mean = r1[0] * (1.f / D_);
  const float var  = r2[0] * (1.f / D_) - mean * mean;
  const float w = rsqrtf(var + 1e-5f);
  #pragma unroll
  for (int i = 0; i < 3; ++i) {
    int d = t + i * 256;
    float v = (y[i] - mean) * w * gamma[d] + beta[d];
    if (outf) outf[(size_t)row * D_ + d] = v;
    if (outb) outb[(size_t)row * D_ + d] = f2bf(v);
  }
}

// ---------------- grouped head via MFMA, LDS-free --------------------------
// grid (G, 7), block 256. Each block: one 16-col f-tile of one group.
__global__ __launch_bounds__(256) void k_head3(const ushort* __restrict__ h,
    const ushort* __restrict__ dupT, const float* __restrict__ dup_bias, float* __restrict__ out) {
  const int g = blockIdx.x, j = blockIdx.y, t = threadIdx.x;
  const int lane = t & 63, wave = t >> 6;
  const int quad = lane >> 4, c = lane & 15;
  const ushort* ap = h + ((size_t)(wave * 16 + c) * G_ + g) * D_;
  const ushort* bp = dupT + ((size_t)g * FP_ + j * 16 + c) * D_;
  f32x4 acc = {};
  #pragma unroll 8
  for (int k0 = 0; k0 < D_; k0 += 32) {
    bf16x8 af = *(const bf16x8*)(ap + k0 + quad * 8);
    bf16x8 bf = *(const bf16x8*)(bp + k0 + quad * 8);
    acc = __builtin_amdgcn_mfma_f32_16x16x32_bf16(af, bf, acc, 0, 0, 0);
  }
  const int f = j * 16 + c;
  if (f >= DF_) return;
  const int n = g * DF_ + f;
  if (n >= NC_) return;
  const float bv = dup_bias[n];
  #pragma unroll
  for (int r = 0; r < 4; ++r) {
    const int b = wave * 16 + quad * 4 + r;
    out[(size_t)b * NC_ + n] = acc[r] + bv;
  }
}

// ---------------------------------------------------------------------------
// workspace layout (bytes)
// ---------------------------------------------------------------------------
static constexpr size_t OFF_AEMB  = 0;          // bf16 [12544,2048] = 51,380,224
static constexpr size_t OFF_ATTNP = 0;          // bf16 [512,112,224] = 25,690,112
static constexpr size_t OFF_VBT   = 25690112;   // bf16 [512,96,224]  = 22,020,096 (end 47,710,208)
static constexpr size_t OFF_FF    = 0;          // bf16 [6400,2048] = 26,214,400
static constexpr size_t OFF_FFO   = 26214400;   // f32  [6400,768]  = 19,660,800 (end 45,875,200)
static constexpr size_t OFF_WEMB  = 51380224;   // bf16 3,145,728
static constexpr size_t OFF_MEM   = 54525952;   // bf16 [12544,768] = 19,267,584
static constexpr size_t OFF_WK    = 73793536;   // 1,179,648   (wk|wv contiguous = fused 1536x768)
static constexpr size_t OFF_WV    = 74973184;   // 1,179,648
static constexpr size_t OFF_WO    = 76152832;   // 1,179,648
static constexpr size_t OFF_W1    = 77332480;   // 3,145,728
static constexpr size_t OFF_W2    = 80478208;   // 3,145,728
static constexpr size_t OFF_DUP   = 83623936;   // bf16 [100,112,768] = 17,203,200
static constexpr size_t OFF_KV    = 100827136;  // bf16 [12544,1536] = 38,535,168 (end 139,362,304)
static constexpr size_t OFF_TGT   = 139362304;  // 307,200
static constexpr size_t OFF_Q     = 139669504;  // bf16 [112,768] = 172,032
static constexpr size_t OFF_BKV   = 139841536;  // f32 [1536] = 6,144
static constexpr size_t OFF_CTX   = 139976704;  // 9,830,400
static constexpr size_t OFF_CTXO  = 149807104;  // 19,660,800
static constexpr size_t OFF_TGT2F = 169467904;  // 19,660,800
static constexpr size_t OFF_TGT2B = 189128704;  // 9,830,400
static constexpr size_t OFF_HB    = 198959104;  // 9,830,400  (end 208,789,504)

extern "C" void kernel_launch(void* const* d_in, const int* in_sizes, int n_in,
                              void* d_out, int out_size, void* d_ws, size_t ws_size,
                              hipStream_t stream) {
  const float* x           = (const float*)d_in[0];
  const float* w_embed     = (const float*)d_in[1];
  const float* b_embed     = (const float*)d_in[2];
  const float* query_embed = (const float*)d_in[3];
  const float* wq          = (const float*)d_in[4];
  const float* bq          = (const float*)d_in[5];
  const float* wk          = (const float*)d_in[6];
  const float* bk          = (const float*)d_in[7];
  const float* wv          = (const float*)d_in[8];
  const float* bv          = (const float*)d_in[9];
  const float* wo          = (const float*)d_in[10];
  const float* bo          = (const float*)d_in[11];
  const float* g1          = (const float*)d_in[12];
  const float* be1         = (const float*)d_in[13];
  const float* g2          = (const float*)d_in[14];
  const float* be2         = (const float*)d_in[15];
  const float* g3          = (const float*)d_in[16];
  const float* be3         = (const float*)d_in[17];
  const float* w1          = (const float*)d_in[18];
  const float* bl1         = (const float*)d_in[19];
  const float* w2          = (const float*)d_in[20];
  const float* bl2         = (const float*)d_in[21];
  const float* dup_pool    = (const float*)d_in[22];
  const float* dup_bias    = (const float*)d_in[23];
  float* out = (float*)d_out;
  char* ws = (char*)d_ws;

  ushort* aemb  = (ushort*)(ws + OFF_AEMB);
  ushort* wembB = (ushort*)(ws + OFF_WEMB);
  ushort* memB  = (ushort*)(ws + OFF_MEM);
  ushort* wkvB  = (ushort*)(ws + OFF_WK);    // fused [1536][768]
  ushort* wkB   = (ushort*)(ws + OFF_WK);
  ushort* wvB   = (ushort*)(ws + OFF_WV);
  ushort* woB   = (ushort*)(ws + OFF_WO);
  ushort* w1B   = (ushort*)(ws + OFF_W1);
  ushort* w2B   = (ushort*)(ws + OFF_W2);
  ushort* dupT  = (ushort*)(ws + OFF_DUP);
  ushort* KVb   = (ushort*)(ws + OFF_KV);
  float*  tgtF  = (float*)(ws + OFF_TGT);
  ushort* qB    = (ushort*)(ws + OFF_Q);
  float*  bkvF  = (float*)(ws + OFF_BKV);
  ushort* attnP = (ushort*)(ws + OFF_ATTNP);
  ushort* VbT   = (ushort*)(ws + OFF_VBT);
  ushort* ctxB  = (ushort*)(ws + OFF_CTX);
  float*  ctxoF = (float*)(ws + OFF_CTXO);
  float*  tgt2F = (float*)(ws + OFF_TGT2F);
  ushort* tgt2B = (ushort*)(ws + OFF_TGT2B);
  ushort* ffB   = (ushort*)(ws + OFF_FF);
  float*  ffoF  = (float*)(ws + OFF_FFO);
  ushort* hB    = (ushort*)(ws + OFF_HB);

  // 1. all weight conversions in one kernel (+ dup transpose, bias pack)
  CvtArgs ca;
  ca.src[0] = w_embed; ca.dst[0] = wembB; ca.n4[0] = D_ * CIN_ / 4;
  ca.src[1] = wk;      ca.dst[1] = wkB;   ca.n4[1] = D_ * D_ / 4;
  ca.src[2] = wv;      ca.dst[2] = wvB;   ca.n4[2] = D_ * D_ / 4;
  ca.src[3] = wo;      ca.dst[3] = woB;   ca.n4[3] = D_ * D_ / 4;
  ca.src[4] = w1;      ca.dst[4] = w1B;   ca.n4[4] = FF_ * D_ / 4;
  ca.src[5] = w2;      ca.dst[5] = w2B;   ca.n4[5] = D_ * FF_ / 4;
  ca.total = ca.n4[0] + ca.n4[1] + ca.n4[2] + ca.n4[3] + ca.n4[4] + ca.n4[5];
  k_cvtall<<<2048, 256, 0, stream>>>(ca);
  k_packb<<<6, 256, 0, stream>>>(bk, bv, bkvF);
  k_dupT<<<dim3(4, 24, G_), 256, 0, stream>>>(dup_pool, dupT);

  // 2. x transpose+convert -> A_emb [B*S, C]
  k_xpose<<<dim3(CIN_ / 32, 7, B_), 256, 0, stream>>>(x, aemb);

  // 3-4. tgt = LN(2*query_embed), qB = bf16(tgt@wq^T + bq) (batch-independent)
  k_tgt<<<G_, 256, 0, stream>>>(query_embed, g1, be1, tgtF);
  k_qproj<<<GP_, 256, 0, stream>>>(tgtF, wq, bq, qB);

  // 5. embed GEMM + relu -> mem bf16 [12544, 768]
  k_gemm<<<dim3(D_ / 128, BS_ / 128), 256, 0, stream>>>(aemb, wembB, b_embed, nullptr, memB,
                                                        BS_, D_, CIN_, 1);
  // 6. fused K|V projection -> bf16 [12544, 1536]
  k_gemm<<<dim3(KVW_ / 128, BS_ / 128), 256, 0, stream>>>(memB, wkvB, bkvF, nullptr, KVb,
                                                          BS_, KVW_, D_, 0);

  // 7. V transpose for PV B-operand
  k_vT<<<dim3(7, 3, B_ * NH_), 256, 0, stream>>>(KVb, VbT);

  // 8-9. MFMA attention
  k_scores<<<dim3(NH_, B_), 256, 0, stream>>>(qB, KVb, attnP);
  k_pv<<<dim3(NH_, B_), 256, 0, stream>>>(attnP, VbT, ctxB);

  // 10. ctx @ wo^T + bo -> fp32 [6400, 768]
  k_gemm<<<dim3(D_ / 128, BG_ / 128), 256, 0, stream>>>(ctxB, woB, bo, ctxoF, nullptr, BG_, D_, D_, 0);

  // 11. tgt2 = LN(tgt + ctxo)
  k_lnres<<<BG_, 256, 0, stream>>>(tgtF, 1, ctxoF, g2, be2, tgt2F, tgt2B);

  // 12-13. FFN
  k_gemm<<<dim3(FF_ / 128, BG_ / 128), 256, 0, stream>>>(tgt2B, w1B, bl1, nullptr, ffB, BG_, FF_, D_, 1);
  k_gemm<<<dim3(D_ / 128, BG_ / 128), 256, 0, stream>>>(ffB, w2B, bl2, ffoF, nullptr, BG_, D_, FF_, 0);

  // 14. h = LN(tgt2 + ffo) -> bf16
  k_lnres<<<BG_, 256, 0, stream>>>(tgt2F, 0, ffoF, g3, be3, nullptr, hB);

  // 15. grouped head -> logits fp32 [64, 9605] via MFMA (LDS-free)
  k_head3<<<dim3(G_, 7), 256, 0, stream>>>(hB, dupT, dup_bias, out);
}

// Round 6
// 622.255 us; speedup vs baseline: 1.1629x; 1.0987x over previous
//
#include <hip/hip_runtime.h>
#include <hip/hip_bf16.h>

// ---------------------------------------------------------------------------
// MLDecoder classification head, MI355X bf16-MFMA implementation.
// B=64, C_IN=2048, H=W=14 (S=196), D=768, FF=2048, G=100, NC=9605, NH=8, HD=96
// ---------------------------------------------------------------------------

#define B_    64
#define CIN_  2048
#define S_    196
#define D_    768
#define FF_   2048
#define G_    100
#define NC_   9605
#define NH_   8
#define HD_   96
#define DF_   97
#define FP_   112          // DF_ padded to 16
#define GP_   112          // G padded to 16
#define SP_   224          // S padded to 32 (7 K-steps) for P / V^T
#define KVW_  1536         // fused K|V row width
#define BS_   (B_ * S_)   // 12544
#define BG_   (B_ * G_)   // 6400

typedef __bf16 bf16x8 __attribute__((ext_vector_type(8)));
typedef float  f32x4  __attribute__((ext_vector_type(4)));

__device__ __forceinline__ float bf2f(ushort u) {
  union { unsigned int i; float f; } v; v.i = ((unsigned int)u) << 16; return v.f;
}
__device__ __forceinline__ ushort f2bf(float f) {
  __hip_bfloat16 h = __float2bfloat16(f);
  return *reinterpret_cast<ushort*>(&h);
}

// async global->LDS, 16 bytes per lane. LDS target must be wave-uniform base
// + lane*16 (our staging layouts satisfy this: lds byte offset == 16*i, i linear in t).
__device__ __forceinline__ void gl2lds16(const ushort* g, ushort* l) {
  __builtin_amdgcn_global_load_lds((const __attribute__((address_space(1))) unsigned int*)g,
                                   (__attribute__((address_space(3))) unsigned int*)l, 16, 0, 0);
}

// ---------------- all weight fp32 -> bf16 converts in ONE kernel -----------
struct CvtArgs {
  const float* src[7];
  ushort*      dst[7];
  int          n4[7];    // float4 chunks per segment
  int          total;    // sum n4
};
__global__ void k_cvtall(CvtArgs a) {
  int i = blockIdx.x * blockDim.x + threadIdx.x;
  const int stride = gridDim.x * blockDim.x;
  for (; i < a.total; i += stride) {
    int seg = 0, off = i;
    while (off >= a.n4[seg]) { off -= a.n4[seg]; ++seg; }
    float4 v = ((const float4*)a.src[seg])[off];
    ushort4 o;
    o.x = f2bf(v.x); o.y = f2bf(v.y); o.z = f2bf(v.z); o.w = f2bf(v.w);
    ((ushort4*)a.dst[seg])[off] = o;
  }
}

// ---------------- pack bk|bv -> bkv [1536] ---------------------------------
__global__ void k_packb(const float* __restrict__ bk, const float* __restrict__ bv,
                        float* __restrict__ bkv) {
  int i = blockIdx.x * 256 + threadIdx.x;
  if (i < D_) bkv[i] = bk[i];
  else if (i < 2 * D_) bkv[i] = bv[i - D_];
}

// ---------------- x [B][C][S] fp32 -> A_emb [B*S][C] bf16 ------------------
// grid (CIN/32, ceil(S/32)=7, B), block 256
__global__ __launch_bounds__(256) void k_xpose(const float* __restrict__ x, ushort* __restrict__ A) {
  __shared__ float tile[32][33];
  const int c0 = blockIdx.x * 32, s0 = blockIdx.y * 32, b = blockIdx.z;
  const int t = threadIdx.x;
  const int tx = t & 31, ty = t >> 5;   // ty in 0..7
  const float* xb = x + (size_t)b * CIN_ * S_;
  #pragma unroll
  for (int r = 0; r < 32; r += 8) {
    int c = c0 + ty + r, s = s0 + tx;
    tile[ty + r][tx] = (s < S_) ? xb[(size_t)c * S_ + s] : 0.f;
  }
  __syncthreads();
  // write: each thread one ushort4 (4 consecutive c) -> 64B per 8 lanes
  const int sl = t >> 3, cq = (t & 7) * 4;
  const int s = s0 + sl;
  if (s < S_) {
    ushort4 o;
    o.x = f2bf(tile[cq + 0][sl]);
    o.y = f2bf(tile[cq + 1][sl]);
    o.z = f2bf(tile[cq + 2][sl]);
    o.w = f2bf(tile[cq + 3][sl]);
    *(ushort4*)&A[((size_t)(b * S_ + s)) * CIN_ + c0 + cq] = o;
  }
}

// ------- dup_pool [g][d=768][f=97] fp32 -> dupT [g][f=112][d=768] bf16 -----
__global__ __launch_bounds__(256) void k_dupT(const float* __restrict__ dup, ushort* __restrict__ dupT) {
  __shared__ float tile[32][33];
  const int f0 = blockIdx.x * 32, d0 = blockIdx.y * 32, g = blockIdx.z;
  const int tx = threadIdx.x & 31, ty = threadIdx.x >> 5;
  #pragma unroll
  for (int r = 0; r < 32; r += 8) {
    int d = d0 + ty + r, f = f0 + tx;
    tile[ty + r][tx] = (f < DF_) ? dup[(size_t)g * D_ * DF_ + (size_t)d * DF_ + f] : 0.f;
  }
  __syncthreads();
  #pragma unroll
  for (int r = 0; r < 32; r += 8) {
    int f = f0 + ty + r, d = d0 + tx;
    if (f < FP_) dupT[((size_t)g * FP_ + f) * D_ + d] = f2bf(tile[tx][ty + r]);
  }
}

// ------- KVb [(b,s)][1536] (V at col 768) -> VbT [(b,h)][96][224], s padded -
// grid (7, 3, 512), block 256
__global__ __launch_bounds__(256) void k_vT(const ushort* __restrict__ KVb, ushort* __restrict__ VbT) {
  __shared__ ushort tile[32][33];
  const int s0 = blockIdx.x * 32, d0 = blockIdx.y * 32, bh = blockIdx.z;
  const int b = bh >> 3, h = bh & 7;
  const int tx = threadIdx.x & 31, ty = threadIdx.x >> 5;
  #pragma unroll
  for (int r = 0; r < 32; r += 8) {
    int s = s0 + ty + r, d = d0 + tx;
    tile[ty + r][tx] = (s < S_) ? KVb[((size_t)(b * S_ + s)) * KVW_ + D_ + h * HD_ + d] : (ushort)0;
  }
  __syncthreads();
  #pragma unroll
  for (int r = 0; r < 32; r += 8) {
    int d = d0 + ty + r, s = s0 + tx;
    VbT[((size_t)bh * HD_ + d) * SP_ + s] = tile[tx][ty + r];
  }
}

// -------- tgt = LN(2*query_embed)*g1 + be1: fp32 [100,768] + bf16 [128,768] -
// grid 128; rows >= 100 write bf16 zeros (padding for the q-projection GEMM).
__global__ __launch_bounds__(256) void k_tgt(const float* __restrict__ qe,
    const float* __restrict__ g1, const float* __restrict__ be1,
    float* __restrict__ tgt, ushort* __restrict__ tgtB) {
  const int g = blockIdx.x, t = threadIdx.x;
  if (g >= G_) {
    for (int d = t; d < D_; d += 256) tgtB[(size_t)g * D_ + d] = 0;
    return;
  }
  __shared__ float r1[256], r2[256];
  float y[3]; float s = 0.f, sq = 0.f;
  const float* row = qe + (size_t)g * D_;
  #pragma unroll
  for (int i = 0; i < 3; ++i) { float v = 2.f * row[t + i * 256]; y[i] = v; s += v; sq += v * v; }
  r1[t] = s; r2[t] = sq; __syncthreads();
  for (int o = 128; o > 0; o >>= 1) { if (t < o) { r1[t] += r1[t + o]; r2[t] += r2[t + o]; } __syncthreads(); }
  const float mean = r1[0] * (1.f / D_);
  const float var  = r2[0] * (1.f / D_) - mean * mean;
  const float w = rsqrtf(var + 1e-5f);
  #pragma unroll
  for (int i = 0; i < 3; ++i) {
    int d = t + i * 256;
    float v = (y[i] - mean) * w * g1[d] + be1[d];
    tgt[(size_t)g * D_ + d] = v;
    tgtB[(size_t)g * D_ + d] = f2bf(v);
  }
}

// ---------------- bf16 MFMA GEMM: C[M,N] = A[M,K] * B[N,K]^T + bias --------
// 128x128 tile, BK=32 (row stride 64 B = 16 banks -> free 2-way aliasing only;
// BK=64 = 32 banks put every row at bank 0 and tripled conflicts: R4 regression).
// 1-D grid with XCD-aware swizzle: all N-tiles of an M-tile land on the same
// XCD (l%8) so the A-tile is fetched into one L2, not 6-12 copies (R5: embed
// FETCH_SIZE was 157 MB vs 54 ideal).
__global__ __launch_bounds__(256) void k_gemm(const ushort* __restrict__ A, const ushort* __restrict__ B,
    const float* __restrict__ bias, float* __restrict__ Cf, ushort* __restrict__ Cb,
    int N, int K, int nbx, int nm, int relu) {
  const int l = blockIdx.x;
  const int mb = (l >> 3) / nbx * 8 + (l & 7);
  const int nb = (l >> 3) % nbx;
  if (mb >= nm) return;
  __shared__ ushort As[128 * 32];
  __shared__ ushort Bs[128 * 32];
  const int t = threadIdx.x;
  const int m0 = mb * 128, n0 = nb * 128;
  const int lane = t & 63, wave = t >> 6;
  const int quad = lane >> 4, lrow = lane & 15;
  const int wr = (wave >> 1) * 64, wc = (wave & 1) * 64;
  const int srow = t >> 2, scol = (t & 3) * 8;
  f32x4 acc[4][4] = {};
  for (int k0 = 0; k0 < K; k0 += 32) {
    const ushort* ag = A + (size_t)(m0 + srow) * K + k0 + scol;
    const ushort* bg = B + (size_t)(n0 + srow) * K + k0 + scol;
    gl2lds16(ag,                    &As[srow * 32 + scol]);
    gl2lds16(ag + (size_t)64 * K,   &As[(srow + 64) * 32 + scol]);
    gl2lds16(bg,                    &Bs[srow * 32 + scol]);
    gl2lds16(bg + (size_t)64 * K,   &Bs[(srow + 64) * 32 + scol]);
    __syncthreads();
    bf16x8 af[4], bfr[4];
    #pragma unroll
    for (int i = 0; i < 4; ++i) af[i] = *(const bf16x8*)&As[(wr + i * 16 + lrow) * 32 + quad * 8];
    #pragma unroll
    for (int j = 0; j < 4; ++j) bfr[j] = *(const bf16x8*)&Bs[(wc + j * 16 + lrow) * 32 + quad * 8];
    #pragma unroll
    for (int i = 0; i < 4; ++i)
      #pragma unroll
      for (int j = 0; j < 4; ++j)
        acc[i][j] = __builtin_amdgcn_mfma_f32_16x16x32_bf16(af[i], bfr[j], acc[i][j], 0, 0, 0);
    __syncthreads();
  }
  #pragma unroll
  for (int i = 0; i < 4; ++i) {
    #pragma unroll
    for (int j = 0; j < 4; ++j) {
      const int gcol = n0 + wc + j * 16 + lrow;
      const float bv = bias ? bias[gcol] : 0.f;
      #pragma unroll
      for (int r = 0; r < 4; ++r) {
        const int grow = m0 + wr + i * 16 + quad * 4 + r;
        float v = acc[i][j][r] + bv;
        if (relu) v = fmaxf(v, 0.f);
        if (Cf) Cf[(size_t)grow * N + gcol] = v;
        else    Cb[(size_t)grow * N + gcol] = f2bf(v);
      }
    }
  }
}
static inline int swz_grid(int nm, int nbx) { return ((nm + 7) & ~7) * nbx; }

// ---------------- scores + in-register softmax -> P bf16 [bh][112][224] ----
// grid (NH, B), block 256. MFMA QK^T, K staged via global_load_lds (stride KVW_).
__global__ __launch_bounds__(256) void k_scores(const ushort* __restrict__ qB,
    const ushort* __restrict__ KVb, ushort* __restrict__ attnP) {
  __shared__ ushort Ks[208 * HD_];   // 39936 B
  const int h = blockIdx.x, b = blockIdx.y, t = threadIdx.x;
  const int bh = b * NH_ + h;
  const int lane = t & 63, wave = t >> 6;
  const int quad = lane >> 4, c = lane & 15;
  // stage K rows 0..207 (rows >=196 read in-bounds-of-ws garbage, masked below)
  for (int i = t; i < 208 * 12; i += 256) {
    int r = i / 12, col = (i % 12) * 8;
    gl2lds16(KVb + ((size_t)(b * S_ + r)) * KVW_ + h * HD_ + col, &Ks[i * 8]);
  }
  __syncthreads();
  const float scale = 0.1020620726f;  // 1/sqrt(96)
  for (int ii = wave; ii < 7; ii += 4) {
    f32x4 acc[13] = {};
    bf16x8 af[3];
    #pragma unroll
    for (int ks = 0; ks < 3; ++ks)
      af[ks] = *(const bf16x8*)(qB + ((size_t)(ii * 16 + c)) * D_ + h * HD_ + ks * 32 + quad * 8);
    #pragma unroll
    for (int j = 0; j < 13; ++j) {
      #pragma unroll
      for (int ks = 0; ks < 3; ++ks) {
        bf16x8 bf = *(const bf16x8*)&Ks[(j * 16 + c) * HD_ + ks * 32 + quad * 8];
        acc[j] = __builtin_amdgcn_mfma_f32_16x16x32_bf16(af[ks], bf, acc[j], 0, 0, 0);
      }
    }
    // softmax: row g = ii*16 + quad*4 + r lives in the 16-lane cluster (c = s-offset)
    float m[4] = {-1e30f, -1e30f, -1e30f, -1e30f};
    #pragma unroll
    for (int j = 0; j < 13; ++j)
      #pragma unroll
      for (int r = 0; r < 4; ++r) {
        float v = acc[j][r] * scale;
        if (j == 12 && c >= 4) v = -1e30f;   // mask padded s in 196..207
        acc[j][r] = v;
        m[r] = fmaxf(m[r], v);
      }
    #pragma unroll
    for (int r = 0; r < 4; ++r) {
      m[r] = fmaxf(m[r], __shfl_xor(m[r], 1));
      m[r] = fmaxf(m[r], __shfl_xor(m[r], 2));
      m[r] = fmaxf(m[r], __shfl_xor(m[r], 4));
      m[r] = fmaxf(m[r], __shfl_xor(m[r], 8));
    }
    float l[4] = {0.f, 0.f, 0.f, 0.f};
    #pragma unroll
    for (int j = 0; j < 13; ++j)
      #pragma unroll
      for (int r = 0; r < 4; ++r) {
        float e = __expf(acc[j][r] - m[r]);
        acc[j][r] = e; l[r] += e;
      }
    #pragma unroll
    for (int r = 0; r < 4; ++r) {
      l[r] += __shfl_xor(l[r], 1);
      l[r] += __shfl_xor(l[r], 2);
      l[r] += __shfl_xor(l[r], 4);
      l[r] += __shfl_xor(l[r], 8);
      l[r] = 1.f / l[r];
    }
    #pragma unroll
    for (int j = 0; j < 13; ++j)
      #pragma unroll
      for (int r = 0; r < 4; ++r) {
        const int g = ii * 16 + quad * 4 + r;
        attnP[((size_t)bh * GP_ + g) * SP_ + j * 16 + c] = f2bf(acc[j][r] * l[r]);
      }
  }
}

// ---------------- ctx = P @ V via MFMA, V^T staged in LDS ------------------
// grid (NH, B), block 256. P A-frags direct from global.
__global__ __launch_bounds__(256) void k_pv(const ushort* __restrict__ attnP,
    const ushort* __restrict__ VbT, ushort* __restrict__ ctx) {
  __shared__ ushort Vs[HD_ * SP_];   // 43008 B
  const int h = blockIdx.x, b = blockIdx.y, t = threadIdx.x;
  const int bh = b * NH_ + h;
  const int lane = t & 63, wave = t >> 6;
  const int quad = lane >> 4, c = lane & 15;
  const ushort* vsrc = VbT + (size_t)bh * HD_ * SP_;
  for (int i = t; i < HD_ * SP_ / 8; i += 256)   // 2688 chunks
    gl2lds16(vsrc + (size_t)i * 8, &Vs[i * 8]);
  __syncthreads();
  for (int ii = wave; ii < 7; ii += 4) {
    bf16x8 af[7];
    #pragma unroll
    for (int k = 0; k < 7; ++k)
      af[k] = *(const bf16x8*)(attnP + ((size_t)bh * GP_ + ii * 16 + c) * SP_ + k * 32 + quad * 8);
    #pragma unroll
    for (int j = 0; j < 6; ++j) {
      f32x4 acc = {};
      #pragma unroll
      for (int k = 0; k < 7; ++k) {
        bf16x8 bf = *(const bf16x8*)&Vs[(j * 16 + c) * SP_ + k * 32 + quad * 8];
        acc = __builtin_amdgcn_mfma_f32_16x16x32_bf16(af[k], bf, acc, 0, 0, 0);
      }
      #pragma unroll
      for (int r = 0; r < 4; ++r) {
        const int g = ii * 16 + quad * 4 + r;
        if (g < G_)
          ctx[((size_t)(b * G_ + g)) * D_ + h * HD_ + j * 16 + c] = f2bf(acc[r]);
      }
    }
  }
}

// ---------------- residual + LayerNorm -------------------------------------
// transb: bf16 out written transposed as [g][b][768] (for the head's A-operand)
__global__ __launch_bounds__(256) void k_lnres(const float* __restrict__ resid, int resid_mod,
    const float* __restrict__ add, const float* __restrict__ gamma, const float* __restrict__ beta,
    float* __restrict__ outf, ushort* __restrict__ outb, int transb) {
  const int row = blockIdx.x, t = threadIdx.x;
  __shared__ float r1[256], r2[256];
  const float* rrow = resid + (size_t)(resid_mod ? (row % G_) : row) * D_;
  const float* arow = add + (size_t)row * D_;
  float y[3]; float s = 0.f, sq = 0.f;
  #pragma unroll
  for (int i = 0; i < 3; ++i) {
    int d = t + i * 256;
    float v = rrow[d] + arow[d];
    y[i] = v; s += v; sq += v * v;
  }
  r1[t] = s; r2[t] = sq; __syncthreads();
  for (int o = 128; o > 0; o >>= 1) { if (t < o) { r1[t] += r1[t + o]; r2[t] += r2[t + o]; } __syncthreads(); }
  const float mean = r1[0] * (1.f / D_);
  const float var  = r2[0] * (1.f / D_) - mean * mean;
  const float w = rsqrtf(var + 1e-5f);
  const size_t orow = transb ? ((size_t)(row % G_) * B_ + row / G_) : (size_t)row;
  #pragma unroll
  for (int i = 0; i < 3; ++i) {
    int d = t + i * 256;
    float v = (y[i] - mean) * w * gamma[d] + beta[d];
    if (outf) outf[(size_t)row * D_ + d] = v;
    if (outb) outb[orow * D_ + d] = f2bf(v);
  }
}

// ---------------- grouped head via MFMA, LDS-free, coalesced ---------------
// grid (G, 7), block 256. hT layout [g][64][768]: a wave's 64 lanes read 16
// full 64B lines per frag load (quad k-offsets land in the same line).
__global__ __launch_bounds__(256) void k_head4(const ushort* __restrict__ hT,
    const ushort* __restrict__ dupT, const float* __restrict__ dup_bias, float* __restrict__ out) {
  const int g = blockIdx.x, j = blockIdx.y, t = threadIdx.x;
  const int lane = t & 63, wave = t >> 6;
  const int quad = lane >> 4, c = lane & 15;
  const ushort* ap = hT + ((size_t)g * B_ + wave * 16 + c) * D_;
  const ushort* bp = dupT + ((size_t)g * FP_ + j * 16 + c) * D_;
  f32x4 acc = {};
  #pragma unroll 8
  for (int k0 = 0; k0 < D_; k0 += 32) {
    bf16x8 af = *(const bf16x8*)(ap + k0 + quad * 8);
    bf16x8 bf = *(const bf16x8*)(bp + k0 + quad * 8);
    acc = __builtin_amdgcn_mfma_f32_16x16x32_bf16(af, bf, acc, 0, 0, 0);
  }
  const int f = j * 16 + c;
  if (f >= DF_) return;
  const int n = g * DF_ + f;
  if (n >= NC_) return;
  const float bv = dup_bias[n];
  #pragma unroll
  for (int r = 0; r < 4; ++r) {
    const int b = wave * 16 + quad * 4 + r;
    out[(size_t)b * NC_ + n] = acc[r] + bv;
  }
}

// ---------------------------------------------------------------------------
// workspace layout (bytes)
// ---------------------------------------------------------------------------
static constexpr size_t OFF_AEMB  = 0;          // bf16 [12544,2048] = 51,380,224
static constexpr size_t OFF_ATTNP = 0;          // bf16 [512,112,224] = 25,690,112
static constexpr size_t OFF_VBT   = 25690112;   // bf16 [512,96,224]  = 22,020,096 (end 47,710,208)
static constexpr size_t OFF_FF    = 0;          // bf16 [6400,2048] = 26,214,400
static constexpr size_t OFF_FFO   = 26214400;   // f32  [6400,768]  = 19,660,800 (end 45,875,200)
static constexpr size_t OFF_WEMB  = 51380224;   // bf16 3,145,728
static constexpr size_t OFF_MEM   = 54525952;   // bf16 [12544,768] = 19,267,584
static constexpr size_t OFF_WK    = 73793536;   // 1,179,648   (wk|wv contiguous = fused 1536x768)
static constexpr size_t OFF_WV    = 74973184;   // 1,179,648
static constexpr size_t OFF_WO    = 76152832;   // 1,179,648
static constexpr size_t OFF_W1    = 77332480;   // 3,145,728
static constexpr size_t OFF_W2    = 80478208;   // 3,145,728
static constexpr size_t OFF_DUP   = 83623936;   // bf16 [100,112,768] = 17,203,200
static constexpr size_t OFF_KV    = 100827136;  // bf16 [12544,1536] = 38,535,168 (end 139,362,304)
static constexpr size_t OFF_TGT   = 139362304;  // f32 [100,768] = 307,200
static constexpr size_t OFF_TGTB  = 139669504;  // bf16 [128,768] = 196,608
static constexpr size_t OFF_Q     = 139866112;  // bf16 [128,768] = 196,608
static constexpr size_t OFF_BKV   = 140062720;  // f32 [1536] = 6,144
static constexpr size_t OFF_CTX   = 140068864;  // bf16 9,830,400 (also wqB early: dead before k_pv)
static constexpr size_t OFF_WQ    = OFF_CTX;    // bf16 [768,768] = 1,179,648 (consumed before ctx written)
static constexpr size_t OFF_CTXO  = 149899264;  // 19,660,800
static constexpr size_t OFF_TGT2F = 169560064;  // 19,660,800
static constexpr size_t OFF_TGT2B = 189220864;  // 9,830,400
static constexpr size_t OFF_HB    = 199051264;  // bf16 [100,64,768] = 9,830,400 (end 208,881,664)

extern "C" void kernel_launch(void* const* d_in, const int* in_sizes, int n_in,
                              void* d_out, int out_size, void* d_ws, size_t ws_size,
                              hipStream_t stream) {
  const float* x           = (const float*)d_in[0];
  const float* w_embed     = (const float*)d_in[1];
  const float* b_embed     = (const float*)d_in[2];
  const float* query_embed = (const float*)d_in[3];
  const float* wq          = (const float*)d_in[4];
  const float* bq          = (const float*)d_in[5];
  const float* wk          = (const float*)d_in[6];
  const float* bk          = (const float*)d_in[7];
  const float* wv          = (const float*)d_in[8];
  const float* bv          = (const float*)d_in[9];
  const float* wo          = (const float*)d_in[10];
  const float* bo          = (const float*)d_in[11];
  const float* g1          = (const float*)d_in[12];
  const float* be1         = (const float*)d_in[13];
  const float* g2          = (const float*)d_in[14];
  const float* be2         = (const float*)d_in[15];
  const float* g3          = (const float*)d_in[16];
  const float* be3         = (const float*)d_in[17];
  const float* w1          = (const float*)d_in[18];
  const float* bl1         = (const float*)d_in[19];
  const float* w2          = (const float*)d_in[20];
  const float* bl2         = (const float*)d_in[21];
  const float* dup_pool    = (const float*)d_in[22];
  const float* dup_bias    = (const float*)d_in[23];
  float* out = (float*)d_out;
  char* ws = (char*)d_ws;

  ushort* aemb  = (ushort*)(ws + OFF_AEMB);
  ushort* wembB = (ushort*)(ws + OFF_WEMB);
  ushort* memB  = (ushort*)(ws + OFF_MEM);
  ushort* wkvB  = (ushort*)(ws + OFF_WK);    // fused [1536][768]
  ushort* wkB   = (ushort*)(ws + OFF_WK);
  ushort* wvB   = (ushort*)(ws + OFF_WV);
  ushort* woB   = (ushort*)(ws + OFF_WO);
  ushort* w1B   = (ushort*)(ws + OFF_W1);
  ushort* w2B   = (ushort*)(ws + OFF_W2);
  ushort* wqB   = (ushort*)(ws + OFF_WQ);
  ushort* dupT  = (ushort*)(ws + OFF_DUP);
  ushort* KVb   = (ushort*)(ws + OFF_KV);
  float*  tgtF  = (float*)(ws + OFF_TGT);
  ushort* tgtB  = (ushort*)(ws + OFF_TGTB);
  ushort* qB    = (ushort*)(ws + OFF_Q);
  float*  bkvF  = (float*)(ws + OFF_BKV);
  ushort* attnP = (ushort*)(ws + OFF_ATTNP);
  ushort* VbT   = (ushort*)(ws + OFF_VBT);
  ushort* ctxB  = (ushort*)(ws + OFF_CTX);
  float*  ctxoF = (float*)(ws + OFF_CTXO);
  float*  tgt2F = (float*)(ws + OFF_TGT2F);
  ushort* tgt2B = (ushort*)(ws + OFF_TGT2B);
  ushort* ffB   = (ushort*)(ws + OFF_FF);
  float*  ffoF  = (float*)(ws + OFF_FFO);
  ushort* hT    = (ushort*)(ws + OFF_HB);

  // 1. all weight conversions in one kernel (+ dup transpose, bias pack)
  CvtArgs ca;
  ca.src[0] = w_embed; ca.dst[0] = wembB; ca.n4[0] = D_ * CIN_ / 4;
  ca.src[1] = wk;      ca.dst[1] = wkB;   ca.n4[1] = D_ * D_ / 4;
  ca.src[2] = wv;      ca.dst[2] = wvB;   ca.n4[2] = D_ * D_ / 4;
  ca.src[3] = wo;      ca.dst[3] = woB;   ca.n4[3] = D_ * D_ / 4;
  ca.src[4] = w1;      ca.dst[4] = w1B;   ca.n4[4] = FF_ * D_ / 4;
  ca.src[5] = w2;      ca.dst[5] = w2B;   ca.n4[5] = D_ * FF_ / 4;
  ca.src[6] = wq;      ca.dst[6] = wqB;   ca.n4[6] = D_ * D_ / 4;
  ca.total = ca.n4[0] + ca.n4[1] + ca.n4[2] + ca.n4[3] + ca.n4[4] + ca.n4[5] + ca.n4[6];
  k_cvtall<<<2048, 256, 0, stream>>>(ca);
  k_packb<<<6, 256, 0, stream>>>(bk, bv, bkvF);
  k_dupT<<<dim3(4, 24, G_), 256, 0, stream>>>(dup_pool, dupT);

  // 2. x transpose+convert -> A_emb [B*S, C]
  k_xpose<<<dim3(CIN_ / 32, 7, B_), 256, 0, stream>>>(x, aemb);

  // 3. tgt = LN(2*query_embed) -> fp32 [100] + bf16 [128] (padded)
  k_tgt<<<128, 256, 0, stream>>>(query_embed, g1, be1, tgtF, tgtB);

  // 4. qB = bf16(tgt@wq^T + bq) via MFMA (M=128 padded)
  k_gemm<<<swz_grid(1, 6), 256, 0, stream>>>(tgtB, wqB, bq, nullptr, qB, D_, D_, 6, 1, 0);

  // 5. embed GEMM + relu -> mem bf16 [12544, 768]
  k_gemm<<<swz_grid(98, 6), 256, 0, stream>>>(aemb, wembB, b_embed, nullptr, memB, D_, CIN_, 6, 98, 1);

  // 6. fused K|V projection -> bf16 [12544, 1536]
  k_gemm<<<swz_grid(98, 12), 256, 0, stream>>>(memB, wkvB, bkvF, nullptr, KVb, KVW_, D_, 12, 98, 0);

  // 7. V transpose for PV B-operand
  k_vT<<<dim3(7, 3, B_ * NH_), 256, 0, stream>>>(KVb, VbT);

  // 8-9. MFMA attention
  k_scores<<<dim3(NH_, B_), 256, 0, stream>>>(qB, KVb, attnP);
  k_pv<<<dim3(NH_, B_), 256, 0, stream>>>(attnP, VbT, ctxB);

  // 10. ctx @ wo^T + bo -> fp32 [6400, 768]
  k_gemm<<<swz_grid(50, 6), 256, 0, stream>>>(ctxB, woB, bo, ctxoF, nullptr, D_, D_, 6, 50, 0);

  // 11. tgt2 = LN(tgt + ctxo)
  k_lnres<<<BG_, 256, 0, stream>>>(tgtF, 1, ctxoF, g2, be2, tgt2F, tgt2B, 0);

  // 12-13. FFN
  k_gemm<<<swz_grid(50, 16), 256, 0, stream>>>(tgt2B, w1B, bl1, nullptr, ffB, FF_, D_, 16, 50, 1);
  k_gemm<<<swz_grid(50, 6), 256, 0, stream>>>(ffB, w2B, bl2, ffoF, nullptr, D_, FF_, 6, 50, 0);

  // 14. h = LN(tgt2 + ffo) -> bf16 transposed [g][64][768]
  k_lnres<<<BG_, 256, 0, stream>>>(tgt2F, 0, ffoF, g3, be3, nullptr, hT, 1);

  // 15. grouped head -> logits fp32 [64, 9605] via MFMA (coalesced, LDS-free)
  k_head4<<<dim3(G_, 7), 256, 0, stream>>>(hT, dupT, dup_bias, out);
}

// Round 7
// 612.317 us; speedup vs baseline: 1.1818x; 1.0162x over previous
//
#include <hip/hip_runtime.h>
#include <hip/hip_bf16.h>

// ---------------------------------------------------------------------------
// MLDecoder classification head, MI355X bf16-MFMA implementation.
// B=64, C_IN=2048, H=W=14 (S=196), D=768, FF=2048, G=100, NC=9605, NH=8, HD=96
// ---------------------------------------------------------------------------

#define B_    64
#define CIN_  2048
#define S_    196
#define D_    768
#define FF_   2048
#define G_    100
#define NC_   9605
#define NH_   8
#define HD_   96
#define DF_   97
#define FP_   112          // DF_ padded to 16
#define GP_   112          // G padded to 16
#define SP_   224          // S padded to 32 (7 K-steps) for P / V^T
#define BS_   (B_ * S_)   // 12544
#define BG_   (B_ * G_)   // 6400

typedef __bf16 bf16x8 __attribute__((ext_vector_type(8)));
typedef float  f32x4  __attribute__((ext_vector_type(4)));

__device__ __forceinline__ float bf2f(ushort u) {
  union { unsigned int i; float f; } v; v.i = ((unsigned int)u) << 16; return v.f;
}
__device__ __forceinline__ ushort f2bf(float f) {
  __hip_bfloat16 h = __float2bfloat16(f);
  return *reinterpret_cast<ushort*>(&h);
}

// async global->LDS, 16 bytes per lane. LDS target must be wave-uniform base
// + lane*16 (our staging layouts satisfy this: lds byte offset == 16*i, i linear in t).
__device__ __forceinline__ void gl2lds16(const ushort* g, ushort* l) {
  __builtin_amdgcn_global_load_lds((const __attribute__((address_space(1))) unsigned int*)g,
                                   (__attribute__((address_space(3))) unsigned int*)l, 16, 0, 0);
}

// ---------------- all weight fp32 -> bf16 converts in ONE kernel -----------
struct CvtArgs {
  const float* src[7];
  ushort*      dst[7];
  int          n4[7];    // float4 chunks per segment
  int          total;    // sum n4
};
__global__ void k_cvtall(CvtArgs a) {
  int i = blockIdx.x * blockDim.x + threadIdx.x;
  const int stride = gridDim.x * blockDim.x;
  for (; i < a.total; i += stride) {
    int seg = 0, off = i;
    while (off >= a.n4[seg]) { off -= a.n4[seg]; ++seg; }
    float4 v = ((const float4*)a.src[seg])[off];
    ushort4 o;
    o.x = f2bf(v.x); o.y = f2bf(v.y); o.z = f2bf(v.z); o.w = f2bf(v.w);
    ((ushort4*)a.dst[seg])[off] = o;
  }
}

// ---------------- x [B][C][S] fp32 -> A_emb [B*S][C] bf16 ------------------
// grid (CIN/32, ceil(S/32)=7, B), block 256
__global__ __launch_bounds__(256) void k_xpose(const float* __restrict__ x, ushort* __restrict__ A) {
  __shared__ float tile[32][33];
  const int c0 = blockIdx.x * 32, s0 = blockIdx.y * 32, b = blockIdx.z;
  const int t = threadIdx.x;
  const int tx = t & 31, ty = t >> 5;   // ty in 0..7
  const float* xb = x + (size_t)b * CIN_ * S_;
  #pragma unroll
  for (int r = 0; r < 32; r += 8) {
    int c = c0 + ty + r, s = s0 + tx;
    tile[ty + r][tx] = (s < S_) ? xb[(size_t)c * S_ + s] : 0.f;
  }
  __syncthreads();
  // write: each thread one ushort4 (4 consecutive c) -> 64B per 8 lanes
  const int sl = t >> 3, cq = (t & 7) * 4;
  const int s = s0 + sl;
  if (s < S_) {
    ushort4 o;
    o.x = f2bf(tile[cq + 0][sl]);
    o.y = f2bf(tile[cq + 1][sl]);
    o.z = f2bf(tile[cq + 2][sl]);
    o.w = f2bf(tile[cq + 3][sl]);
    *(ushort4*)&A[((size_t)(b * S_ + s)) * CIN_ + c0 + cq] = o;
  }
}

// ------- dup_pool [g][d=768][f=97] fp32 -> dupT [g][f=112][d=768] bf16 -----
__global__ __launch_bounds__(256) void k_dupT(const float* __restrict__ dup, ushort* __restrict__ dupT) {
  __shared__ float tile[32][33];
  const int f0 = blockIdx.x * 32, d0 = blockIdx.y * 32, g = blockIdx.z;
  const int tx = threadIdx.x & 31, ty = threadIdx.x >> 5;
  #pragma unroll
  for (int r = 0; r < 32; r += 8) {
    int d = d0 + ty + r, f = f0 + tx;
    tile[ty + r][tx] = (f < DF_) ? dup[(size_t)g * D_ * DF_ + (size_t)d * DF_ + f] : 0.f;
  }
  __syncthreads();
  #pragma unroll
  for (int r = 0; r < 32; r += 8) {
    int f = f0 + ty + r, d = d0 + tx;
    if (f < FP_) dupT[((size_t)g * FP_ + f) * D_ + d] = f2bf(tile[tx][ty + r]);
  }
}

// -------- tgt = LN(2*query_embed)*g1 + be1: fp32 [100,768] + bf16 [128,768] -
// grid 128; rows >= 100 write bf16 zeros (padding for the q-projection GEMM).
__global__ __launch_bounds__(256) void k_tgt(const float* __restrict__ qe,
    const float* __restrict__ g1, const float* __restrict__ be1,
    float* __restrict__ tgt, ushort* __restrict__ tgtB) {
  const int g = blockIdx.x, t = threadIdx.x;
  if (g >= G_) {
    for (int d = t; d < D_; d += 256) tgtB[(size_t)g * D_ + d] = 0;
    return;
  }
  __shared__ float r1[256], r2[256];
  float y[3]; float s = 0.f, sq = 0.f;
  const float* row = qe + (size_t)g * D_;
  #pragma unroll
  for (int i = 0; i < 3; ++i) { float v = 2.f * row[t + i * 256]; y[i] = v; s += v; sq += v * v; }
  r1[t] = s; r2[t] = sq; __syncthreads();
  for (int o = 128; o > 0; o >>= 1) { if (t < o) { r1[t] += r1[t + o]; r2[t] += r2[t + o]; } __syncthreads(); }
  const float mean = r1[0] * (1.f / D_);
  const float var  = r2[0] * (1.f / D_) - mean * mean;
  const float w = rsqrtf(var + 1e-5f);
  #pragma unroll
  for (int i = 0; i < 3; ++i) {
    int d = t + i * 256;
    float v = (y[i] - mean) * w * g1[d] + be1[d];
    tgt[(size_t)g * D_ + d] = v;
    tgtB[(size_t)g * D_ + d] = f2bf(v);
  }
}

// ---------------- bf16 MFMA GEMM: C[M,N] = A[M,K] * B[N,K]^T + bias --------
// 128x128 tile, BK=32 (row stride 64 B = 16 banks -> free 2-way aliasing only;
// BK=64 = 32 banks put every row at bank 0 and tripled conflicts: R4 regression).
// 1-D grid with XCD-aware swizzle (R6: embed FETCH 157 -> 38 MB).
// KV mode (Vt != null): cols >= 768 are the V projection, written TRANSPOSED
// into VbT [bh][hd][s] (4 C-frag regs = 4 consecutive s, never crossing a
// batch boundary since s % 4 == 0 and 196 % 4 == 0 -> one ushort4 store).
// bias2 (if set) supplies bias for cols >= 768.
__global__ __launch_bounds__(256) void k_gemm(const ushort* __restrict__ A, const ushort* __restrict__ B,
    const float* __restrict__ bias, const float* __restrict__ bias2,
    float* __restrict__ Cf, ushort* __restrict__ Cb, ushort* __restrict__ Vt,
    int N, int K, int nbx, int nm, int relu) {
  const int l = blockIdx.x;
  const int mb = (l >> 3) / nbx * 8 + (l & 7);
  const int nb = (l >> 3) % nbx;
  if (mb >= nm) return;
  __shared__ ushort As[128 * 32];
  __shared__ ushort Bs[128 * 32];
  const int t = threadIdx.x;
  const int m0 = mb * 128, n0 = nb * 128;
  const int lane = t & 63, wave = t >> 6;
  const int quad = lane >> 4, lrow = lane & 15;
  const int wr = (wave >> 1) * 64, wc = (wave & 1) * 64;
  const int srow = t >> 2, scol = (t & 3) * 8;
  f32x4 acc[4][4] = {};
  for (int k0 = 0; k0 < K; k0 += 32) {
    const ushort* ag = A + (size_t)(m0 + srow) * K + k0 + scol;
    const ushort* bg = B + (size_t)(n0 + srow) * K + k0 + scol;
    gl2lds16(ag,                    &As[srow * 32 + scol]);
    gl2lds16(ag + (size_t)64 * K,   &As[(srow + 64) * 32 + scol]);
    gl2lds16(bg,                    &Bs[srow * 32 + scol]);
    gl2lds16(bg + (size_t)64 * K,   &Bs[(srow + 64) * 32 + scol]);
    __syncthreads();
    bf16x8 af[4], bfr[4];
    #pragma unroll
    for (int i = 0; i < 4; ++i) af[i] = *(const bf16x8*)&As[(wr + i * 16 + lrow) * 32 + quad * 8];
    #pragma unroll
    for (int j = 0; j < 4; ++j) bfr[j] = *(const bf16x8*)&Bs[(wc + j * 16 + lrow) * 32 + quad * 8];
    #pragma unroll
    for (int i = 0; i < 4; ++i)
      #pragma unroll
      for (int j = 0; j < 4; ++j)
        acc[i][j] = __builtin_amdgcn_mfma_f32_16x16x32_bf16(af[i], bfr[j], acc[i][j], 0, 0, 0);
    __syncthreads();
  }
  #pragma unroll
  for (int i = 0; i < 4; ++i) {
    #pragma unroll
    for (int j = 0; j < 4; ++j) {
      const int gcol = n0 + wc + j * 16 + lrow;
      const float bv = (bias2 && gcol >= D_) ? bias2[gcol - D_] : (bias ? bias[gcol] : 0.f);
      if (Vt && gcol >= D_) {
        const int dv = gcol - D_, hh = dv / HD_, hd = dv % HD_;
        const int row0 = m0 + wr + i * 16 + quad * 4;
        const int bb = row0 / S_, ss = row0 % S_;
        ushort4 o;
        o.x = f2bf(acc[i][j][0] + bv);
        o.y = f2bf(acc[i][j][1] + bv);
        o.z = f2bf(acc[i][j][2] + bv);
        o.w = f2bf(acc[i][j][3] + bv);
        *(ushort4*)&Vt[((size_t)(bb * NH_ + hh) * HD_ + hd) * SP_ + ss] = o;
      } else {
        #pragma unroll
        for (int r = 0; r < 4; ++r) {
          const int grow = m0 + wr + i * 16 + quad * 4 + r;
          float v = acc[i][j][r] + bv;
          if (relu) v = fmaxf(v, 0.f);
          if (Cf) Cf[(size_t)grow * N + gcol] = v;
          else    Cb[(size_t)grow * N + gcol] = f2bf(v);
        }
      }
    }
  }
}
static inline int swz_grid(int nm, int nbx) { return ((nm + 7) & ~7) * nbx; }

// ---------------- fused attention: QK^T + softmax + PV ---------------------
// grid (NH, B), block 256. K staged to LDS; P lives in regs then LDS (union
// with K buffer); V B-frags read straight from global VbT (each elem once).
// Zero-padding lives on the P side: s in [196,224) written as 0.
__global__ __launch_bounds__(256) void k_attn(const ushort* __restrict__ qB,
    const ushort* __restrict__ Kb, const ushort* __restrict__ VbT, ushort* __restrict__ ctx) {
  __shared__ ushort lds[GP_ * SP_];   // 50176 B; first 39936 B doubles as K stage
  ushort* Ks = lds;
  ushort* Ps = lds;
  const int h = blockIdx.x, b = blockIdx.y, t = threadIdx.x;
  const int bh = b * NH_ + h;
  const int lane = t & 63, wave = t >> 6;
  const int quad = lane >> 4, c = lane & 15;
  // stage K rows 0..207 (rows >= 196 read in-ws garbage, masked below)
  for (int i = t; i < 208 * 12; i += 256) {
    int r = i / 12, col = (i % 12) * 8;
    gl2lds16(Kb + ((size_t)(b * S_ + r)) * D_ + h * HD_ + col, &Ks[i * 8]);
  }
  __syncthreads();
  const float scale = 0.1020620726f;  // 1/sqrt(96)
  f32x4 p[2][13];
  #pragma unroll
  for (int rep = 0; rep < 2; ++rep) {
    const int ii = wave + rep * 4;
    if (ii >= 7) continue;
    bf16x8 af[3];
    #pragma unroll
    for (int ks = 0; ks < 3; ++ks)
      af[ks] = *(const bf16x8*)(qB + ((size_t)(ii * 16 + c)) * D_ + h * HD_ + ks * 32 + quad * 8);
    #pragma unroll
    for (int j = 0; j < 13; ++j) {
      f32x4 a = {};
      #pragma unroll
      for (int ks = 0; ks < 3; ++ks) {
        bf16x8 bf = *(const bf16x8*)&Ks[(j * 16 + c) * HD_ + ks * 32 + quad * 8];
        a = __builtin_amdgcn_mfma_f32_16x16x32_bf16(af[ks], bf, a, 0, 0, 0);
      }
      p[rep][j] = a;
    }
    // in-register softmax over the 16-lane cluster (c = s-offset)
    float m[4] = {-1e30f, -1e30f, -1e30f, -1e30f};
    #pragma unroll
    for (int j = 0; j < 13; ++j)
      #pragma unroll
      for (int r = 0; r < 4; ++r) {
        float v = p[rep][j][r] * scale;
        if (j == 12 && c >= 4) v = -1e30f;   // mask padded s 196..207 (kills NaN too)
        p[rep][j][r] = v;
        m[r] = fmaxf(m[r], v);
      }
    #pragma unroll
    for (int r = 0; r < 4; ++r) {
      m[r] = fmaxf(m[r], __shfl_xor(m[r], 1));
      m[r] = fmaxf(m[r], __shfl_xor(m[r], 2));
      m[r] = fmaxf(m[r], __shfl_xor(m[r], 4));
      m[r] = fmaxf(m[r], __shfl_xor(m[r], 8));
    }
    float lsum[4] = {0.f, 0.f, 0.f, 0.f};
    #pragma unroll
    for (int j = 0; j < 13; ++j)
      #pragma unroll
      for (int r = 0; r < 4; ++r) {
        float e = __expf(p[rep][j][r] - m[r]);
        p[rep][j][r] = e; lsum[r] += e;
      }
    #pragma unroll
    for (int r = 0; r < 4; ++r) {
      lsum[r] += __shfl_xor(lsum[r], 1);
      lsum[r] += __shfl_xor(lsum[r], 2);
      lsum[r] += __shfl_xor(lsum[r], 4);
      lsum[r] += __shfl_xor(lsum[r], 8);
      lsum[r] = 1.f / lsum[r];
    }
    #pragma unroll
    for (int j = 0; j < 13; ++j)
      #pragma unroll
      for (int r = 0; r < 4; ++r)
        p[rep][j][r] *= lsum[r];
  }
  __syncthreads();   // everyone done reading Ks -> safe to overwrite with Ps
  #pragma unroll
  for (int rep = 0; rep < 2; ++rep) {
    const int ii = wave + rep * 4;
    if (ii >= 7) continue;
    #pragma unroll
    for (int r = 0; r < 4; ++r) {
      const int g = ii * 16 + quad * 4 + r;
      #pragma unroll
      for (int j = 0; j < 13; ++j)
        Ps[g * SP_ + j * 16 + c] = f2bf(p[rep][j][r]);
      Ps[g * SP_ + 208 + c] = 0;   // pad s 208..223
    }
  }
  __syncthreads();
  #pragma unroll
  for (int rep = 0; rep < 2; ++rep) {
    const int ii = wave + rep * 4;
    if (ii >= 7) continue;
    bf16x8 af[7];
    #pragma unroll
    for (int k = 0; k < 7; ++k)
      af[k] = *(const bf16x8*)&Ps[(ii * 16 + c) * SP_ + k * 32 + quad * 8];
    #pragma unroll
    for (int j = 0; j < 6; ++j) {
      f32x4 acc = {};
      #pragma unroll
      for (int k = 0; k < 7; ++k) {
        bf16x8 bf = *(const bf16x8*)(VbT + ((size_t)bh * HD_ + j * 16 + c) * SP_ + k * 32 + quad * 8);
        acc = __builtin_amdgcn_mfma_f32_16x16x32_bf16(af[k], bf, acc, 0, 0, 0);
      }
      #pragma unroll
      for (int r = 0; r < 4; ++r) {
        const int g = ii * 16 + quad * 4 + r;
        if (g < G_)
          ctx[((size_t)(b * G_ + g)) * D_ + h * HD_ + j * 16 + c] = f2bf(acc[r]);
      }
    }
  }
}

// ---------------- residual + LayerNorm -------------------------------------
// transb: bf16 out written transposed as [g][b][768] (for the head's A-operand)
__global__ __launch_bounds__(256) void k_lnres(const float* __restrict__ resid, int resid_mod,
    const float* __restrict__ add, const float* __restrict__ gamma, const float* __restrict__ beta,
    float* __restrict__ outf, ushort* __restrict__ outb, int transb) {
  const int row = blockIdx.x, t = threadIdx.x;
  __shared__ float r1[256], r2[256];
  const float* rrow = resid + (size_t)(resid_mod ? (row % G_) : row) * D_;
  const float* arow = add + (size_t)row * D_;
  float y[3]; float s = 0.f, sq = 0.f;
  #pragma unroll
  for (int i = 0; i < 3; ++i) {
    int d = t + i * 256;
    float v = rrow[d] + arow[d];
    y[i] = v; s += v; sq += v * v;
  }
  r1[t] = s; r2[t] = sq; __syncthreads();
  for (int o = 128; o > 0; o >>= 1) { if (t < o) { r1[t] += r1[t + o]; r2[t] += r2[t + o]; } __syncthreads(); }
  const float mean = r1[0] * (1.f / D_);
  const float var  = r2[0] * (1.f / D_) - mean * mean;
  const float w = rsqrtf(var + 1e-5f);
  const size_t orow = transb ? ((size_t)(row % G_) * B_ + row / G_) : (size_t)row;
  #pragma unroll
  for (int i = 0; i < 3; ++i) {
    int d = t + i * 256;
    float v = (y[i] - mean) * w * gamma[d] + beta[d];
    if (outf) outf[(size_t)row * D_ + d] = v;
    if (outb) outb[orow * D_ + d] = f2bf(v);
  }
}

// ---------------- grouped head via MFMA, LDS-free, coalesced ---------------
// grid (G, 7), block 256. hT layout [g][64][768]: a wave's 64 lanes read 16
// full 64B lines per frag load (quad k-offsets land in the same line).
__global__ __launch_bounds__(256) void k_head4(const ushort* __restrict__ hT,
    const ushort* __restrict__ dupT, const float* __restrict__ dup_bias, float* __restrict__ out) {
  const int g = blockIdx.x, j = blockIdx.y, t = threadIdx.x;
  const int lane = t & 63, wave = t >> 6;
  const int quad = lane >> 4, c = lane & 15;
  const ushort* ap = hT + ((size_t)g * B_ + wave * 16 + c) * D_;
  const ushort* bp = dupT + ((size_t)g * FP_ + j * 16 + c) * D_;
  f32x4 acc = {};
  #pragma unroll 8
  for (int k0 = 0; k0 < D_; k0 += 32) {
    bf16x8 af = *(const bf16x8*)(ap + k0 + quad * 8);
    bf16x8 bf = *(const bf16x8*)(bp + k0 + quad * 8);
    acc = __builtin_amdgcn_mfma_f32_16x16x32_bf16(af, bf, acc, 0, 0, 0);
  }
  const int f = j * 16 + c;
  if (f >= DF_) return;
  const int n = g * DF_ + f;
  if (n >= NC_) return;
  const float bv = dup_bias[n];
  #pragma unroll
  for (int r = 0; r < 4; ++r) {
    const int b = wave * 16 + quad * 4 + r;
    out[(size_t)b * NC_ + n] = acc[r] + bv;
  }
}

// ---------------------------------------------------------------------------
// workspace layout (bytes)
// region 0 timeline: aemb (until embed GEMM) -> VbT (KV epilogue .. attn) ->
//                    ffB/ffoF (FFN)
// ---------------------------------------------------------------------------
static constexpr size_t OFF_AEMB  = 0;          // bf16 [12544,2048] = 51,380,224
static constexpr size_t OFF_VBT   = 0;          // bf16 [512,96,224]  = 22,020,096
static constexpr size_t OFF_FF    = 0;          // bf16 [6400,2048] = 26,214,400
static constexpr size_t OFF_FFO   = 26214400;   // f32  [6400,768]  = 19,660,800 (end 45,875,200)
static constexpr size_t OFF_WEMB  = 51380224;   // bf16 3,145,728
static constexpr size_t OFF_MEM   = 54525952;   // bf16 [12544,768] = 19,267,584
static constexpr size_t OFF_WK    = 73793536;   // 1,179,648   (wk|wv contiguous = fused 1536x768)
static constexpr size_t OFF_WV    = 74973184;   // 1,179,648
static constexpr size_t OFF_WO    = 76152832;   // 1,179,648
static constexpr size_t OFF_W1    = 77332480;   // 3,145,728
static constexpr size_t OFF_W2    = 80478208;   // 3,145,728
static constexpr size_t OFF_DUP   = 83623936;   // bf16 [100,112,768] = 17,203,200
static constexpr size_t OFF_KB    = 100827136;  // bf16 [12544,768] = 19,267,584
static constexpr size_t OFF_TGT   = 139362304;  // f32 [100,768] = 307,200
static constexpr size_t OFF_TGTB  = 139669504;  // bf16 [128,768] = 196,608
static constexpr size_t OFF_Q     = 139866112;  // bf16 [128,768] = 196,608
static constexpr size_t OFF_CTX   = 140068864;  // bf16 9,830,400 (also wqB early: dead before attn)
static constexpr size_t OFF_WQ    = OFF_CTX;    // bf16 [768,768] = 1,179,648 (consumed before ctx written)
static constexpr size_t OFF_CTXO  = 149899264;  // 19,660,800
static constexpr size_t OFF_TGT2F = 169560064;  // 19,660,800
static constexpr size_t OFF_TGT2B = 189220864;  // 9,830,400
static constexpr size_t OFF_HB    = 199051264;  // bf16 [100,64,768] = 9,830,400 (end 208,881,664)

extern "C" void kernel_launch(void* const* d_in, const int* in_sizes, int n_in,
                              void* d_out, int out_size, void* d_ws, size_t ws_size,
                              hipStream_t stream) {
  const float* x           = (const float*)d_in[0];
  const float* w_embed     = (const float*)d_in[1];
  const float* b_embed     = (const float*)d_in[2];
  const float* query_embed = (const float*)d_in[3];
  const float* wq          = (const float*)d_in[4];
  const float* bq          = (const float*)d_in[5];
  const float* wk          = (const float*)d_in[6];
  const float* bk          = (const float*)d_in[7];
  const float* wv          = (const float*)d_in[8];
  const float* bv          = (const float*)d_in[9];
  const float* wo          = (const float*)d_in[10];
  const float* bo          = (const float*)d_in[11];
  const float* g1          = (const float*)d_in[12];
  const float* be1         = (const float*)d_in[13];
  const float* g2          = (const float*)d_in[14];
  const float* be2         = (const float*)d_in[15];
  const float* g3          = (const float*)d_in[16];
  const float* be3         = (const float*)d_in[17];
  const float* w1          = (const float*)d_in[18];
  const float* bl1         = (const float*)d_in[19];
  const float* w2          = (const float*)d_in[20];
  const float* bl2         = (const float*)d_in[21];
  const float* dup_pool    = (const float*)d_in[22];
  const float* dup_bias    = (const float*)d_in[23];
  float* out = (float*)d_out;
  char* ws = (char*)d_ws;

  ushort* aemb  = (ushort*)(ws + OFF_AEMB);
  ushort* wembB = (ushort*)(ws + OFF_WEMB);
  ushort* memB  = (ushort*)(ws + OFF_MEM);
  ushort* wkvB  = (ushort*)(ws + OFF_WK);    // fused [1536][768]
  ushort* wkB   = (ushort*)(ws + OFF_WK);
  ushort* wvB   = (ushort*)(ws + OFF_WV);
  ushort* woB   = (ushort*)(ws + OFF_WO);
  ushort* w1B   = (ushort*)(ws + OFF_W1);
  ushort* w2B   = (ushort*)(ws + OFF_W2);
  ushort* wqB   = (ushort*)(ws + OFF_WQ);
  ushort* dupT  = (ushort*)(ws + OFF_DUP);
  ushort* Kb    = (ushort*)(ws + OFF_KB);
  float*  tgtF  = (float*)(ws + OFF_TGT);
  ushort* tgtB  = (ushort*)(ws + OFF_TGTB);
  ushort* qB    = (ushort*)(ws + OFF_Q);
  ushort* VbT   = (ushort*)(ws + OFF_VBT);
  ushort* ctxB  = (ushort*)(ws + OFF_CTX);
  float*  ctxoF = (float*)(ws + OFF_CTXO);
  float*  tgt2F = (float*)(ws + OFF_TGT2F);
  ushort* tgt2B = (ushort*)(ws + OFF_TGT2B);
  ushort* ffB   = (ushort*)(ws + OFF_FF);
  float*  ffoF  = (float*)(ws + OFF_FFO);
  ushort* hT    = (ushort*)(ws + OFF_HB);

  // 1. all weight conversions in one kernel (+ dup transpose)
  CvtArgs ca;
  ca.src[0] = w_embed; ca.dst[0] = wembB; ca.n4[0] = D_ * CIN_ / 4;
  ca.src[1] = wk;      ca.dst[1] = wkB;   ca.n4[1] = D_ * D_ / 4;
  ca.src[2] = wv;      ca.dst[2] = wvB;   ca.n4[2] = D_ * D_ / 4;
  ca.src[3] = wo;      ca.dst[3] = woB;   ca.n4[3] = D_ * D_ / 4;
  ca.src[4] = w1;      ca.dst[4] = w1B;   ca.n4[4] = FF_ * D_ / 4;
  ca.src[5] = w2;      ca.dst[5] = w2B;   ca.n4[5] = D_ * FF_ / 4;
  ca.src[6] = wq;      ca.dst[6] = wqB;   ca.n4[6] = D_ * D_ / 4;
  ca.total = ca.n4[0] + ca.n4[1] + ca.n4[2] + ca.n4[3] + ca.n4[4] + ca.n4[5] + ca.n4[6];
  k_cvtall<<<2048, 256, 0, stream>>>(ca);
  k_dupT<<<dim3(4, 24, G_), 256, 0, stream>>>(dup_pool, dupT);

  // 2. x transpose+convert -> A_emb [B*S, C]
  k_xpose<<<dim3(CIN_ / 32, 7, B_), 256, 0, stream>>>(x, aemb);

  // 3. tgt = LN(2*query_embed) -> fp32 [100] + bf16 [128] (padded)
  k_tgt<<<128, 256, 0, stream>>>(query_embed, g1, be1, tgtF, tgtB);

  // 4. qB = bf16(tgt@wq^T + bq) via MFMA (M=128 padded)
  k_gemm<<<swz_grid(1, 6), 256, 0, stream>>>(tgtB, wqB, bq, nullptr, nullptr, qB, nullptr,
                                             D_, D_, 6, 1, 0);

  // 5. embed GEMM + relu -> mem bf16 [12544, 768]
  k_gemm<<<swz_grid(98, 6), 256, 0, stream>>>(aemb, wembB, b_embed, nullptr, nullptr, memB, nullptr,
                                              D_, CIN_, 6, 98, 1);

  // 6. fused K|V projection: K -> Kb [12544,768], V -> VbT [512][96][224] transposed
  k_gemm<<<swz_grid(98, 12), 256, 0, stream>>>(memB, wkvB, bk, bv, nullptr, Kb, VbT,
                                               D_, D_, 12, 98, 0);

  // 7. fused attention (QK^T + softmax + PV)
  k_attn<<<dim3(NH_, B_), 256, 0, stream>>>(qB, Kb, VbT, ctxB);

  // 8. ctx @ wo^T + bo -> fp32 [6400, 768]
  k_gemm<<<swz_grid(50, 6), 256, 0, stream>>>(ctxB, woB, bo, nullptr, ctxoF, nullptr, nullptr,
                                              D_, D_, 6, 50, 0);

  // 9. tgt2 = LN(tgt + ctxo)
  k_lnres<<<BG_, 256, 0, stream>>>(tgtF, 1, ctxoF, g2, be2, tgt2F, tgt2B, 0);

  // 10-11. FFN
  k_gemm<<<swz_grid(50, 16), 256, 0, stream>>>(tgt2B, w1B, bl1, nullptr, nullptr, ffB, nullptr,
                                               FF_, D_, 16, 50, 1);
  k_gemm<<<swz_grid(50, 6), 256, 0, stream>>>(ffB, w2B, bl2, nullptr, ffoF, nullptr, nullptr,
                                              D_, FF_, 6, 50, 0);

  // 12. h = LN(tgt2 + ffo) -> bf16 transposed [g][64][768]
  k_lnres<<<BG_, 256, 0, stream>>>(tgt2F, 0, ffoF, g3, be3, nullptr, hT, 1);

  // 13. grouped head -> logits fp32 [64, 9605] via MFMA (coalesced, LDS-free)
  k_head4<<<dim3(G_, 7), 256, 0, stream>>>(hT, dupT, dup_bias, out);
}

// Round 8
// 581.700 us; speedup vs baseline: 1.2440x; 1.0526x over previous
//
#include <hip/hip_runtime.h>
#include <hip/hip_bf16.h>

// ---------------------------------------------------------------------------
// MLDecoder classification head, MI355X bf16-MFMA implementation.
// B=64, C_IN=2048, H=W=14 (S=196), D=768, FF=2048, G=100, NC=9605, NH=8, HD=96
// ---------------------------------------------------------------------------

#define B_    64
#define CIN_  2048
#define S_    196
#define D_    768
#define FF_   2048
#define G_    100
#define NC_   9605
#define NH_   8
#define HD_   96
#define DF_   97
#define FP_   112          // DF_ padded to 16
#define GP_   112          // G padded to 16
#define SP_   224          // S padded to 32 (7 K-steps) for P / V^T
#define BS_   (B_ * S_)   // 12544
#define BG_   (B_ * G_)   // 6400

typedef __bf16 bf16x8 __attribute__((ext_vector_type(8)));
typedef float  f32x4  __attribute__((ext_vector_type(4)));

__device__ __forceinline__ float bf2f(ushort u) {
  union { unsigned int i; float f; } v; v.i = ((unsigned int)u) << 16; return v.f;
}
__device__ __forceinline__ ushort f2bf(float f) {
  __hip_bfloat16 h = __float2bfloat16(f);
  return *reinterpret_cast<ushort*>(&h);
}

// async global->LDS, 16 bytes per lane. LDS target must be wave-uniform base
// + lane*16 (our staging layouts satisfy this: lds byte offset == 16*i, i linear in t).
__device__ __forceinline__ void gl2lds16(const ushort* g, ushort* l) {
  __builtin_amdgcn_global_load_lds((const __attribute__((address_space(1))) unsigned int*)g,
                                   (__attribute__((address_space(3))) unsigned int*)l, 16, 0, 0);
}

// ---------------------------------------------------------------------------
// fused prep: x-transpose + dup-transpose + weight converts + tgt LN
// one dispatch, job selected by block range (R7: these 4 kernels serialized
// with the GPU mostly idle; fused they co-schedule).
// ---------------------------------------------------------------------------
#define XP_BLKS 1792   // xpose: (b, s-tile, c-chunk of 512)
#define DT_BLKS 400    // dupT:  (g, d-chunk of 192)
#define CV_BLKS 512    // cvt:   grid-stride
#define TG_BLKS 128    // tgt LN rows (padded)

struct PrepArgs {
  const float* x;   ushort* aemb;
  const float* dup; ushort* dupT;
  const float* csrc[7]; ushort* cdst[7]; int cn4[7]; int ctotal;
  const float* qe; const float* g1; const float* be1;
  float* tgt; ushort* tgtB;
};

__global__ __launch_bounds__(256) void k_prep(PrepArgs pa) {
  __shared__ float tile[32][33];
  __shared__ float r1[256], r2[256];
  int jid = blockIdx.x;
  const int t = threadIdx.x;

  if (jid < XP_BLKS) {
    // x [B][C][S] -> aemb [(b,s)][C] bf16. 16 c-tiles per block.
    const int b = jid / 28, rem = jid % 28;
    const int s0 = (rem % 7) * 32, cbase = (rem / 7) * 512;
    const int tx = t & 31, ty = t >> 5;
    const int sl = t >> 3, cq = (t & 7) * 4;
    const float* xb = pa.x + (size_t)b * CIN_ * S_;
    for (int cc = 0; cc < 512; cc += 32) {
      const int c0 = cbase + cc;
      #pragma unroll
      for (int r = 0; r < 32; r += 8) {
        int c = c0 + ty + r, s = s0 + tx;
        tile[ty + r][tx] = (s < S_) ? xb[(size_t)c * S_ + s] : 0.f;
      }
      __syncthreads();
      const int s = s0 + sl;
      if (s < S_) {
        ushort4 o;
        o.x = f2bf(tile[cq + 0][sl]); o.y = f2bf(tile[cq + 1][sl]);
        o.z = f2bf(tile[cq + 2][sl]); o.w = f2bf(tile[cq + 3][sl]);
        *(ushort4*)&pa.aemb[((size_t)(b * S_ + s)) * CIN_ + c0 + cq] = o;
      }
      __syncthreads();
    }
    return;
  }
  jid -= XP_BLKS;

  if (jid < DT_BLKS) {
    // dup_pool [g][d][f=97] -> dupT [g][f=112][d] bf16, f zero-padded.
    const int g = jid >> 2, dchunk = jid & 3;
    const int tx = t & 31, ty = t >> 5;
    for (int di = 0; di < 6; ++di) {
      const int d0 = dchunk * 192 + di * 32;
      for (int f0 = 0; f0 < 128; f0 += 32) {
        #pragma unroll
        for (int r = 0; r < 32; r += 8) {
          int d = d0 + ty + r, f = f0 + tx;
          tile[ty + r][tx] = (f < DF_) ? pa.dup[(size_t)g * D_ * DF_ + (size_t)d * DF_ + f] : 0.f;
        }
        __syncthreads();
        #pragma unroll
        for (int r = 0; r < 32; r += 8) {
          int f = f0 + ty + r, d = d0 + tx;
          if (f < FP_) pa.dupT[((size_t)g * FP_ + f) * D_ + d] = f2bf(tile[tx][ty + r]);
        }
        __syncthreads();
      }
    }
    return;
  }
  jid -= DT_BLKS;

  if (jid < CV_BLKS) {
    // bulk fp32 -> bf16 weight converts, grid-stride over 7 segments
    int i = jid * 256 + t;
    const int stride = CV_BLKS * 256;
    for (; i < pa.ctotal; i += stride) {
      int seg = 0, off = i;
      while (off >= pa.cn4[seg]) { off -= pa.cn4[seg]; ++seg; }
      float4 v = ((const float4*)pa.csrc[seg])[off];
      ushort4 o;
      o.x = f2bf(v.x); o.y = f2bf(v.y); o.z = f2bf(v.z); o.w = f2bf(v.w);
      ((ushort4*)pa.cdst[seg])[off] = o;
    }
    return;
  }
  jid -= CV_BLKS;

  // tgt = LN(2*query_embed)*g1 + be1 -> fp32 [100,768] + bf16 [128,768] (pad 0)
  const int g = jid;
  if (g >= G_) {
    for (int d = t; d < D_; d += 256) pa.tgtB[(size_t)g * D_ + d] = 0;
    return;
  }
  float y[3]; float s = 0.f, sq = 0.f;
  const float* row = pa.qe + (size_t)g * D_;
  #pragma unroll
  for (int i = 0; i < 3; ++i) { float v = 2.f * row[t + i * 256]; y[i] = v; s += v; sq += v * v; }
  r1[t] = s; r2[t] = sq; __syncthreads();
  for (int o = 128; o > 0; o >>= 1) { if (t < o) { r1[t] += r1[t + o]; r2[t] += r2[t + o]; } __syncthreads(); }
  const float mean = r1[0] * (1.f / D_);
  const float var  = r2[0] * (1.f / D_) - mean * mean;
  const float w = rsqrtf(var + 1e-5f);
  #pragma unroll
  for (int i = 0; i < 3; ++i) {
    int d = t + i * 256;
    float v = (y[i] - mean) * w * pa.g1[d] + pa.be1[d];
    pa.tgt[(size_t)g * D_ + d] = v;
    pa.tgtB[(size_t)g * D_ + d] = f2bf(v);
  }
}

// ---------------- bf16 MFMA GEMM core: C[M,N] = A[M,K]*B[N,K]^T + bias -----
// 128x128 tile, BK=32 (row stride 64 B = 16 banks -> free 2-way aliasing only;
// BK=64 = 32 banks put every row at bank 0 and tripled conflicts: R4 regression).
// KV mode (Vt != null): cols >= 768 are the V projection, written TRANSPOSED
// into VbT [bh][hd][s] (4 C-frag regs = 4 consecutive s, never crossing a
// batch boundary since s % 4 == 0 and 196 % 4 == 0 -> one ushort4 store).
__device__ __forceinline__ void gemm_core(const ushort* __restrict__ A, const ushort* __restrict__ B,
    const float* __restrict__ bias, const float* __restrict__ bias2,
    float* __restrict__ Cf, ushort* __restrict__ Cb, ushort* __restrict__ Vt,
    int N, int K, int m0, int n0, int relu, ushort* As, ushort* Bs) {
  const int t = threadIdx.x;
  const int lane = t & 63, wave = t >> 6;
  const int quad = lane >> 4, lrow = lane & 15;
  const int wr = (wave >> 1) * 64, wc = (wave & 1) * 64;
  const int srow = t >> 2, scol = (t & 3) * 8;
  f32x4 acc[4][4] = {};
  for (int k0 = 0; k0 < K; k0 += 32) {
    const ushort* ag = A + (size_t)(m0 + srow) * K + k0 + scol;
    const ushort* bg = B + (size_t)(n0 + srow) * K + k0 + scol;
    gl2lds16(ag,                    &As[srow * 32 + scol]);
    gl2lds16(ag + (size_t)64 * K,   &As[(srow + 64) * 32 + scol]);
    gl2lds16(bg,                    &Bs[srow * 32 + scol]);
    gl2lds16(bg + (size_t)64 * K,   &Bs[(srow + 64) * 32 + scol]);
    __syncthreads();
    bf16x8 af[4], bfr[4];
    #pragma unroll
    for (int i = 0; i < 4; ++i) af[i] = *(const bf16x8*)&As[(wr + i * 16 + lrow) * 32 + quad * 8];
    #pragma unroll
    for (int j = 0; j < 4; ++j) bfr[j] = *(const bf16x8*)&Bs[(wc + j * 16 + lrow) * 32 + quad * 8];
    #pragma unroll
    for (int i = 0; i < 4; ++i)
      #pragma unroll
      for (int j = 0; j < 4; ++j)
        acc[i][j] = __builtin_amdgcn_mfma_f32_16x16x32_bf16(af[i], bfr[j], acc[i][j], 0, 0, 0);
    __syncthreads();
  }
  #pragma unroll
  for (int i = 0; i < 4; ++i) {
    #pragma unroll
    for (int j = 0; j < 4; ++j) {
      const int gcol = n0 + wc + j * 16 + lrow;
      const float bv = (bias2 && gcol >= D_) ? bias2[gcol - D_] : (bias ? bias[gcol] : 0.f);
      if (Vt && gcol >= D_) {
        const int dv = gcol - D_, hh = dv / HD_, hd = dv % HD_;
        const int row0 = m0 + wr + i * 16 + quad * 4;
        const int bb = row0 / S_, ss = row0 % S_;
        ushort4 o;
        o.x = f2bf(acc[i][j][0] + bv);
        o.y = f2bf(acc[i][j][1] + bv);
        o.z = f2bf(acc[i][j][2] + bv);
        o.w = f2bf(acc[i][j][3] + bv);
        *(ushort4*)&Vt[((size_t)(bb * NH_ + hh) * HD_ + hd) * SP_ + ss] = o;
      } else {
        #pragma unroll
        for (int r = 0; r < 4; ++r) {
          const int grow = m0 + wr + i * 16 + quad * 4 + r;
          float v = acc[i][j][r] + bv;
          if (relu) v = fmaxf(v, 0.f);
          if (Cf) Cf[(size_t)grow * N + gcol] = v;
          else    Cb[(size_t)grow * N + gcol] = f2bf(v);
        }
      }
    }
  }
}

// 1-D grid with XCD-aware swizzle (R6: embed FETCH 157 -> 38 MB). Optional
// second job (A2 != null) runs in tail blocks (used to fold the tiny q-proj
// into the embed dispatch instead of a whole-GPU-idle 6-block launch).
__global__ __launch_bounds__(256) void k_gemm(const ushort* __restrict__ A, const ushort* __restrict__ B,
    const float* __restrict__ bias, const float* __restrict__ bias2,
    float* __restrict__ Cf, ushort* __restrict__ Cb, ushort* __restrict__ Vt,
    int N, int K, int nbx, int nm, int relu,
    const ushort* __restrict__ A2, const ushort* __restrict__ B2,
    const float* __restrict__ bias_2, ushort* __restrict__ Cb2, int N2, int K2) {
  __shared__ ushort As[128 * 32];
  __shared__ ushort Bs[128 * 32];
  const int l = blockIdx.x;
  const int base = ((nm + 7) & ~7) * nbx;
  if (l >= base) {
    gemm_core(A2, B2, bias_2, nullptr, nullptr, Cb2, nullptr, N2, K2, 0, (l - base) * 128, 0, As, Bs);
    return;
  }
  const int mb = (l >> 3) / nbx * 8 + (l & 7);
  const int nb = (l >> 3) % nbx;
  if (mb >= nm) return;
  gemm_core(A, B, bias, bias2, Cf, Cb, Vt, N, K, mb * 128, nb * 128, relu, As, Bs);
}
static inline int swz_grid(int nm, int nbx) { return ((nm + 7) & ~7) * nbx; }

// ---------------- fused attention: QK^T + softmax + PV ---------------------
// grid (NH, B), block 256. K staged to LDS; P lives in regs then LDS (union
// with K buffer); V B-frags read straight from global VbT (each elem once).
__global__ __launch_bounds__(256) void k_attn(const ushort* __restrict__ qB,
    const ushort* __restrict__ Kb, const ushort* __restrict__ VbT, ushort* __restrict__ ctx) {
  __shared__ ushort lds[GP_ * SP_];   // 50176 B; first 39936 B doubles as K stage
  ushort* Ks = lds;
  ushort* Ps = lds;
  const int h = blockIdx.x, b = blockIdx.y, t = threadIdx.x;
  const int bh = b * NH_ + h;
  const int lane = t & 63, wave = t >> 6;
  const int quad = lane >> 4, c = lane & 15;
  for (int i = t; i < 208 * 12; i += 256) {
    int r = i / 12, col = (i % 12) * 8;
    gl2lds16(Kb + ((size_t)(b * S_ + r)) * D_ + h * HD_ + col, &Ks[i * 8]);
  }
  __syncthreads();
  const float scale = 0.1020620726f;  // 1/sqrt(96)
  f32x4 p[2][13];
  #pragma unroll
  for (int rep = 0; rep < 2; ++rep) {
    const int ii = wave + rep * 4;
    if (ii >= 7) continue;
    bf16x8 af[3];
    #pragma unroll
    for (int ks = 0; ks < 3; ++ks)
      af[ks] = *(const bf16x8*)(qB + ((size_t)(ii * 16 + c)) * D_ + h * HD_ + ks * 32 + quad * 8);
    #pragma unroll
    for (int j = 0; j < 13; ++j) {
      f32x4 a = {};
      #pragma unroll
      for (int ks = 0; ks < 3; ++ks) {
        bf16x8 bf = *(const bf16x8*)&Ks[(j * 16 + c) * HD_ + ks * 32 + quad * 8];
        a = __builtin_amdgcn_mfma_f32_16x16x32_bf16(af[ks], bf, a, 0, 0, 0);
      }
      p[rep][j] = a;
    }
    float m[4] = {-1e30f, -1e30f, -1e30f, -1e30f};
    #pragma unroll
    for (int j = 0; j < 13; ++j)
      #pragma unroll
      for (int r = 0; r < 4; ++r) {
        float v = p[rep][j][r] * scale;
        if (j == 12 && c >= 4) v = -1e30f;   // mask padded s 196..207 (kills NaN too)
        p[rep][j][r] = v;
        m[r] = fmaxf(m[r], v);
      }
    #pragma unroll
    for (int r = 0; r < 4; ++r) {
      m[r] = fmaxf(m[r], __shfl_xor(m[r], 1));
      m[r] = fmaxf(m[r], __shfl_xor(m[r], 2));
      m[r] = fmaxf(m[r], __shfl_xor(m[r], 4));
      m[r] = fmaxf(m[r], __shfl_xor(m[r], 8));
    }
    float lsum[4] = {0.f, 0.f, 0.f, 0.f};
    #pragma unroll
    for (int j = 0; j < 13; ++j)
      #pragma unroll
      for (int r = 0; r < 4; ++r) {
        float e = __expf(p[rep][j][r] - m[r]);
        p[rep][j][r] = e; lsum[r] += e;
      }
    #pragma unroll
    for (int r = 0; r < 4; ++r) {
      lsum[r] += __shfl_xor(lsum[r], 1);
      lsum[r] += __shfl_xor(lsum[r], 2);
      lsum[r] += __shfl_xor(lsum[r], 4);
      lsum[r] += __shfl_xor(lsum[r], 8);
      lsum[r] = 1.f / lsum[r];
    }
    #pragma unroll
    for (int j = 0; j < 13; ++j)
      #pragma unroll
      for (int r = 0; r < 4; ++r)
        p[rep][j][r] *= lsum[r];
  }
  __syncthreads();   // everyone done reading Ks -> safe to overwrite with Ps
  #pragma unroll
  for (int rep = 0; rep < 2; ++rep) {
    const int ii = wave + rep * 4;
    if (ii >= 7) continue;
    #pragma unroll
    for (int r = 0; r < 4; ++r) {
      const int g = ii * 16 + quad * 4 + r;
      #pragma unroll
      for (int j = 0; j < 13; ++j)
        Ps[g * SP_ + j * 16 + c] = f2bf(p[rep][j][r]);
      Ps[g * SP_ + 208 + c] = 0;   // pad s 208..223
    }
  }
  __syncthreads();
  #pragma unroll
  for (int rep = 0; rep < 2; ++rep) {
    const int ii = wave + rep * 4;
    if (ii >= 7) continue;
    bf16x8 af[7];
    #pragma unroll
    for (int k = 0; k < 7; ++k)
      af[k] = *(const bf16x8*)&Ps[(ii * 16 + c) * SP_ + k * 32 + quad * 8];
    #pragma unroll
    for (int j = 0; j < 6; ++j) {
      f32x4 acc = {};
      #pragma unroll
      for (int k = 0; k < 7; ++k) {
        bf16x8 bf = *(const bf16x8*)(VbT + ((size_t)bh * HD_ + j * 16 + c) * SP_ + k * 32 + quad * 8);
        acc = __builtin_amdgcn_mfma_f32_16x16x32_bf16(af[k], bf, acc, 0, 0, 0);
      }
      #pragma unroll
      for (int r = 0; r < 4; ++r) {
        const int g = ii * 16 + quad * 4 + r;
        if (g < G_)
          ctx[((size_t)(b * G_ + g)) * D_ + h * HD_ + j * 16 + c] = f2bf(acc[r]);
      }
    }
  }
}

// ---------------- residual + LayerNorm (add-input bf16) --------------------
// transb: bf16 out written transposed as [g][b][768] (for the head's A-operand)
__global__ __launch_bounds__(256) void k_lnres(const float* __restrict__ resid, int resid_mod,
    const ushort* __restrict__ addB, const float* __restrict__ gamma, const float* __restrict__ beta,
    float* __restrict__ outf, ushort* __restrict__ outb, int transb) {
  const int row = blockIdx.x, t = threadIdx.x;
  __shared__ float r1[256], r2[256];
  const float* rrow = resid + (size_t)(resid_mod ? (row % G_) : row) * D_;
  const ushort* arow = addB + (size_t)row * D_;
  float y[3]; float s = 0.f, sq = 0.f;
  #pragma unroll
  for (int i = 0; i < 3; ++i) {
    int d = t + i * 256;
    float v = rrow[d] + bf2f(arow[d]);
    y[i] = v; s += v; sq += v * v;
  }
  r1[t] = s; r2[t] = sq; __syncthreads();
  for (int o = 128; o > 0; o >>= 1) { if (t < o) { r1[t] += r1[t + o]; r2[t] += r2[t + o]; } __syncthreads(); }
  const float mean = r1[0] * (1.f / D_);
  const float var  = r2[0] * (1.f / D_) - mean * mean;
  const float w = rsqrtf(var + 1e-5f);
  const size_t orow = transb ? ((size_t)(row % G_) * B_ + row / G_) : (size_t)row;
  #pragma unroll
  for (int i = 0; i < 3; ++i) {
    int d = t + i * 256;
    float v = (y[i] - mean) * w * gamma[d] + beta[d];
    if (outf) outf[(size_t)row * D_ + d] = v;
    if (outb) outb[orow * D_ + d] = f2bf(v);
  }
}

// ---------------- grouped head via MFMA, LDS-free, coalesced ---------------
// grid (G, 7), block 256. hT layout [g][64][768]: a wave's 64 lanes read 16
// full 64B lines per frag load (quad k-offsets land in the same line).
__global__ __launch_bounds__(256) void k_head4(const ushort* __restrict__ hT,
    const ushort* __restrict__ dupT, const float* __restrict__ dup_bias, float* __restrict__ out) {
  const int g = blockIdx.x, j = blockIdx.y, t = threadIdx.x;
  const int lane = t & 63, wave = t >> 6;
  const int quad = lane >> 4, c = lane & 15;
  const ushort* ap = hT + ((size_t)g * B_ + wave * 16 + c) * D_;
  const ushort* bp = dupT + ((size_t)g * FP_ + j * 16 + c) * D_;
  f32x4 acc = {};
  #pragma unroll 8
  for (int k0 = 0; k0 < D_; k0 += 32) {
    bf16x8 af = *(const bf16x8*)(ap + k0 + quad * 8);
    bf16x8 bf = *(const bf16x8*)(bp + k0 + quad * 8);
    acc = __builtin_amdgcn_mfma_f32_16x16x32_bf16(af, bf, acc, 0, 0, 0);
  }
  const int f = j * 16 + c;
  if (f >= DF_) return;
  const int n = g * DF_ + f;
  if (n >= NC_) return;
  const float bv = dup_bias[n];
  #pragma unroll
  for (int r = 0; r < 4; ++r) {
    const int b = wave * 16 + quad * 4 + r;
    out[(size_t)b * NC_ + n] = acc[r] + bv;
  }
}

// ---------------------------------------------------------------------------
// workspace layout (bytes)
// region 0 timeline: aemb (until embed GEMM) -> VbT (KV epilogue .. attn) ->
//                    ffB/ffoB (FFN)
// ---------------------------------------------------------------------------
static constexpr size_t OFF_AEMB  = 0;          // bf16 [12544,2048] = 51,380,224
static constexpr size_t OFF_VBT   = 0;          // bf16 [512,96,224]  = 22,020,096
static constexpr size_t OFF_FF    = 0;          // bf16 [6400,2048] = 26,214,400
static constexpr size_t OFF_FFO   = 26214400;   // bf16 [6400,768]  = 9,830,400 (end 36,044,800)
static constexpr size_t OFF_WEMB  = 51380224;   // bf16 3,145,728
static constexpr size_t OFF_MEM   = 54525952;   // bf16 [12544,768] = 19,267,584
static constexpr size_t OFF_WK    = 73793536;   // 1,179,648   (wk|wv contiguous = fused 1536x768)
static constexpr size_t OFF_WV    = 74973184;   // 1,179,648
static constexpr size_t OFF_WO    = 76152832;   // 1,179,648
static constexpr size_t OFF_W1    = 77332480;   // 3,145,728
static constexpr size_t OFF_W2    = 80478208;   // 3,145,728
static constexpr size_t OFF_DUP   = 83623936;   // bf16 [100,112,768] = 17,203,200
static constexpr size_t OFF_KB    = 100827136;  // bf16 [12544,768] = 19,267,584
static constexpr size_t OFF_TGT   = 139362304;  // f32 [100,768] = 307,200
static constexpr size_t OFF_TGTB  = 139669504;  // bf16 [128,768] = 196,608
static constexpr size_t OFF_Q     = 139866112;  // bf16 [128,768] = 196,608
static constexpr size_t OFF_CTX   = 140068864;  // bf16 9,830,400 (also wqB early: dead before attn)
static constexpr size_t OFF_WQ    = OFF_CTX;    // bf16 [768,768] = 1,179,648 (consumed before ctx written)
static constexpr size_t OFF_CTXO  = 149899264;  // bf16 [6400,768] = 9,830,400
static constexpr size_t OFF_TGT2F = 169560064;  // f32 19,660,800
static constexpr size_t OFF_TGT2B = 189220864;  // bf16 9,830,400
static constexpr size_t OFF_HB    = 199051264;  // bf16 [100,64,768] = 9,830,400 (end 208,881,664)

extern "C" void kernel_launch(void* const* d_in, const int* in_sizes, int n_in,
                              void* d_out, int out_size, void* d_ws, size_t ws_size,
                              hipStream_t stream) {
  const float* x           = (const float*)d_in[0];
  const float* w_embed     = (const float*)d_in[1];
  const float* b_embed     = (const float*)d_in[2];
  const float* query_embed = (const float*)d_in[3];
  const float* wq          = (const float*)d_in[4];
  const float* bq          = (const float*)d_in[5];
  const float* wk          = (const float*)d_in[6];
  const float* bk          = (const float*)d_in[7];
  const float* wv          = (const float*)d_in[8];
  const float* bv          = (const float*)d_in[9];
  const float* wo          = (const float*)d_in[10];
  const float* bo          = (const float*)d_in[11];
  const float* g1          = (const float*)d_in[12];
  const float* be1         = (const float*)d_in[13];
  const float* g2          = (const float*)d_in[14];
  const float* be2         = (const float*)d_in[15];
  const float* g3          = (const float*)d_in[16];
  const float* be3         = (const float*)d_in[17];
  const float* w1          = (const float*)d_in[18];
  const float* bl1         = (const float*)d_in[19];
  const float* w2          = (const float*)d_in[20];
  const float* bl2         = (const float*)d_in[21];
  const float* dup_pool    = (const float*)d_in[22];
  const float* dup_bias    = (const float*)d_in[23];
  float* out = (float*)d_out;
  char* ws = (char*)d_ws;

  ushort* aemb  = (ushort*)(ws + OFF_AEMB);
  ushort* wembB = (ushort*)(ws + OFF_WEMB);
  ushort* memB  = (ushort*)(ws + OFF_MEM);
  ushort* wkvB  = (ushort*)(ws + OFF_WK);    // fused [1536][768]
  ushort* wkB   = (ushort*)(ws + OFF_WK);
  ushort* wvB   = (ushort*)(ws + OFF_WV);
  ushort* woB   = (ushort*)(ws + OFF_WO);
  ushort* w1B   = (ushort*)(ws + OFF_W1);
  ushort* w2B   = (ushort*)(ws + OFF_W2);
  ushort* wqB   = (ushort*)(ws + OFF_WQ);
  ushort* dupT  = (ushort*)(ws + OFF_DUP);
  ushort* Kb    = (ushort*)(ws + OFF_KB);
  float*  tgtF  = (float*)(ws + OFF_TGT);
  ushort* tgtB  = (ushort*)(ws + OFF_TGTB);
  ushort* qB    = (ushort*)(ws + OFF_Q);
  ushort* VbT   = (ushort*)(ws + OFF_VBT);
  ushort* ctxB  = (ushort*)(ws + OFF_CTX);
  ushort* ctxoB = (ushort*)(ws + OFF_CTXO);
  float*  tgt2F = (float*)(ws + OFF_TGT2F);
  ushort* tgt2B = (ushort*)(ws + OFF_TGT2B);
  ushort* ffB   = (ushort*)(ws + OFF_FF);
  ushort* ffoB  = (ushort*)(ws + OFF_FFO);
  ushort* hT    = (ushort*)(ws + OFF_HB);

  // 1. fused prep: x-transpose, dup-transpose, weight converts, tgt LN
  PrepArgs pa;
  pa.x = x; pa.aemb = aemb;
  pa.dup = dup_pool; pa.dupT = dupT;
  pa.csrc[0] = w_embed; pa.cdst[0] = wembB; pa.cn4[0] = D_ * CIN_ / 4;
  pa.csrc[1] = wk;      pa.cdst[1] = wkB;   pa.cn4[1] = D_ * D_ / 4;
  pa.csrc[2] = wv;      pa.cdst[2] = wvB;   pa.cn4[2] = D_ * D_ / 4;
  pa.csrc[3] = wo;      pa.cdst[3] = woB;   pa.cn4[3] = D_ * D_ / 4;
  pa.csrc[4] = w1;      pa.cdst[4] = w1B;   pa.cn4[4] = FF_ * D_ / 4;
  pa.csrc[5] = w2;      pa.cdst[5] = w2B;   pa.cn4[5] = D_ * FF_ / 4;
  pa.csrc[6] = wq;      pa.cdst[6] = wqB;   pa.cn4[6] = D_ * D_ / 4;
  pa.ctotal = pa.cn4[0] + pa.cn4[1] + pa.cn4[2] + pa.cn4[3] + pa.cn4[4] + pa.cn4[5] + pa.cn4[6];
  pa.qe = query_embed; pa.g1 = g1; pa.be1 = be1; pa.tgt = tgtF; pa.tgtB = tgtB;
  k_prep<<<XP_BLKS + DT_BLKS + CV_BLKS + TG_BLKS, 256, 0, stream>>>(pa);

  // 2. embed GEMM + relu -> mem bf16; tail blocks: qB = tgtB@wq^T + bq
  k_gemm<<<swz_grid(98, 6) + 6, 256, 0, stream>>>(aemb, wembB, b_embed, nullptr,
                                                  nullptr, memB, nullptr, D_, CIN_, 6, 98, 1,
                                                  tgtB, wqB, bq, qB, D_, D_);

  // 3. fused K|V projection: K -> Kb [12544,768], V -> VbT [512][96][224] transposed
  k_gemm<<<swz_grid(98, 12), 256, 0, stream>>>(memB, wkvB, bk, bv, nullptr, Kb, VbT,
                                               D_, D_, 12, 98, 0,
                                               nullptr, nullptr, nullptr, nullptr, 0, 0);

  // 4. fused attention (QK^T + softmax + PV)
  k_attn<<<dim3(NH_, B_), 256, 0, stream>>>(qB, Kb, VbT, ctxB);

  // 5. ctx @ wo^T + bo -> bf16 [6400, 768]
  k_gemm<<<swz_grid(50, 6), 256, 0, stream>>>(ctxB, woB, bo, nullptr, nullptr, ctxoB, nullptr,
                                              D_, D_, 6, 50, 0,
                                              nullptr, nullptr, nullptr, nullptr, 0, 0);

  // 6. tgt2 = LN(tgt + ctxo)
  k_lnres<<<BG_, 256, 0, stream>>>(tgtF, 1, ctxoB, g2, be2, tgt2F, tgt2B, 0);

  // 7-8. FFN
  k_gemm<<<swz_grid(50, 16), 256, 0, stream>>>(tgt2B, w1B, bl1, nullptr, nullptr, ffB, nullptr,
                                               FF_, D_, 16, 50, 1,
                                               nullptr, nullptr, nullptr, nullptr, 0, 0);
  k_gemm<<<swz_grid(50, 6), 256, 0, stream>>>(ffB, w2B, bl2, nullptr, nullptr, ffoB, nullptr,
                                              D_, FF_, 6, 50, 0,
                                              nullptr, nullptr, nullptr, nullptr, 0, 0);

  // 9. h = LN(tgt2 + ffo) -> bf16 transposed [g][64][768]
  k_lnres<<<BG_, 256, 0, stream>>>(tgt2F, 0, ffoB, g3, be3, nullptr, hT, 1);

  // 10. grouped head -> logits fp32 [64, 9605] via MFMA (coalesced, LDS-free)
  k_head4<<<dim3(G_, 7), 256, 0, stream>>>(hT, dupT, dup_bias, out);
}